// Round 10
// baseline (1402.229 us; speedup 1.0000x reference)
//
#include <hip/hip_runtime.h>

#define Bb 64
#define Nn 128
#define Ee 2048
#define Hh 256
#define Ll 6
#define TN 8192
#define TE 131072
#define EDGE 50
#define EKPAD 64

typedef __attribute__((ext_vector_type(4))) float f32x4;
typedef __attribute__((ext_vector_type(8))) __bf16 bf16x8;
typedef __attribute__((ext_vector_type(8))) unsigned short ushort8;

__device__ inline float b2f(unsigned short u) {
    union { unsigned u; float f; } v; v.u = ((unsigned)u) << 16; return v.f;
}
__device__ inline unsigned short f2b(float f) {
    union { float f; unsigned u; } v; v.f = f;
    unsigned r = v.u + 0x7fffu + ((v.u >> 16) & 1u);
    return (unsigned short)(r >> 16);
}
__device__ inline float spf(float x) {
    return fmaxf(x, 0.f) + __logf(1.f + __expf(-fabsf(x)));
}
__device__ inline float sspf(float x) {
    return spf(x) - 0.69314718055994530942f;
}

// ---------------- GEMM (R4-verified): C = act(A @ WT^T + bias), N fixed 256 ----
template <int ACT, int OUTMODE, int TM>
__global__ __launch_bounds__(256)
void gemm_k(const unsigned short* __restrict__ A,
            const unsigned short* __restrict__ WT,
            const float* __restrict__ bias,
            unsigned short* __restrict__ Cb,
            float* __restrict__ Xf,
            unsigned short* __restrict__ Xb,
            int M, int K)
{
    constexpr int BK  = 64;
    constexpr int TNc = 128;
    constexpr int MR  = TM / 32;
    constexpr int NR  = 4;
    constexpr int STAGE_B = (TM + TNc) * BK * 2;
    constexpr int EPI_B   = (OUTMODE == 2) ? TM * TNc * 4 : TM * TNc * 2;
    constexpr int SMEM_B  = STAGE_B > EPI_B ? STAGE_B : EPI_B;

    __shared__ __align__(16) unsigned char smem[SMEM_B];
    unsigned short* As = (unsigned short*)smem;
    unsigned short* Bs = As + TM * BK;

    const int tid  = threadIdx.x;
    const int lane = tid & 63;
    const int w    = tid >> 6;
    const int wr   = w >> 1, wc = w & 1;
    const int r16  = lane & 15;
    const int kg   = lane >> 4;

    const long brow = (long)blockIdx.y * TM;
    const int  bcol = blockIdx.x * TNc;

    constexpr int ACH = TM / 8;
    constexpr int NCH = ACH + TNc / 8;
    constexpr int IPW = NCH / 4;
    const int lrow  = lane >> 3;
    const int lslot = lane & 7;

    f32x4 acc[MR][NR];
#pragma unroll
    for (int m = 0; m < MR; ++m)
#pragma unroll
        for (int n = 0; n < NR; ++n) acc[m][n] = f32x4{0.f, 0.f, 0.f, 0.f};

    for (int k0 = 0; k0 < K; k0 += BK) {
        __syncthreads();
#pragma unroll
        for (int i = 0; i < IPW; ++i) {
            const int c    = w * IPW + i;
            const bool isA = c < ACH;
            const int cc   = isA ? c : c - ACH;
            const int srow = cc * 8 + lrow;
            const int kch  = lslot ^ (srow & 7);
            const unsigned short* gp = isA
                ? A  + (brow + srow) * (long)K + k0 + kch * 8
                : WT + (bcol + srow) * (long)K + k0 + kch * 8;
            unsigned short* lp = (isA ? As : Bs) + cc * 512;
            __builtin_amdgcn_global_load_lds(
                (const __attribute__((address_space(1))) void*)gp,
                (__attribute__((address_space(3))) void*)lp, 16, 0, 0);
        }
        __syncthreads();

        bf16x8 a[MR][2], b[NR][2];
#pragma unroll
        for (int m = 0; m < MR; ++m) {
            const int row = wr * (MR * 16) + m * 16 + r16;
            const unsigned short* base = As + row * BK;
#pragma unroll
            for (int kk = 0; kk < 2; ++kk) {
                const int slot = (kk * 4 + kg) ^ (row & 7);
                a[m][kk] = *(const bf16x8*)(base + slot * 8);
            }
        }
#pragma unroll
        for (int n = 0; n < NR; ++n) {
            const int row = wc * 64 + n * 16 + r16;
            const unsigned short* base = Bs + row * BK;
#pragma unroll
            for (int kk = 0; kk < 2; ++kk) {
                const int slot = (kk * 4 + kg) ^ (row & 7);
                b[n][kk] = *(const bf16x8*)(base + slot * 8);
            }
        }
#pragma unroll
        for (int kk = 0; kk < 2; ++kk)
#pragma unroll
            for (int m = 0; m < MR; ++m)
#pragma unroll
                for (int n = 0; n < NR; ++n)
                    acc[m][n] = __builtin_amdgcn_mfma_f32_16x16x32_bf16(
                        b[n][kk], a[m][kk], acc[m][n], 0, 0, 0);
    }

    __syncthreads();

    if (OUTMODE != 2) {
#pragma unroll
        for (int m = 0; m < MR; ++m) {
            const int row = wr * (MR * 16) + m * 16 + r16;
#pragma unroll
            for (int n = 0; n < NR; ++n) {
                const int colL = wc * 64 + n * 16 + kg * 4;
                const f32x4 bv = *(const f32x4*)(bias + bcol + colL);
                float v0 = acc[m][n][0] + bv[0];
                float v1 = acc[m][n][1] + bv[1];
                float v2 = acc[m][n][2] + bv[2];
                float v3 = acc[m][n][3] + bv[3];
                if (ACT) { v0 = sspf(v0); v1 = sspf(v1); v2 = sspf(v2); v3 = sspf(v3); }
                uint2 p;
                p.x = (unsigned)f2b(v0) | ((unsigned)f2b(v1) << 16);
                p.y = (unsigned)f2b(v2) | ((unsigned)f2b(v3) << 16);
                const int off = (row * 256 + colL * 2) ^ ((row & 7) << 4);
                *(uint2*)(smem + off) = p;
            }
        }
        __syncthreads();
        constexpr int ITER = TM / 16;
#pragma unroll
        for (int q = 0; q < ITER; ++q) {
            const int flat = q * 4096 + tid * 16;
            const int row = flat >> 8, cbyte = flat & 255;
            uint4 d = *(const uint4*)(smem + ((row * 256 + cbyte) ^ ((row & 7) << 4)));
            *(uint4*)((unsigned char*)Cb + (brow + row) * 512 + bcol * 2 + cbyte) = d;
        }
    } else {
#pragma unroll
        for (int m = 0; m < MR; ++m) {
            const int row = wr * (MR * 16) + m * 16 + r16;
#pragma unroll
            for (int n = 0; n < NR; ++n) {
                const int colL = wc * 64 + n * 16 + kg * 4;
                const f32x4 bv = *(const f32x4*)(bias + bcol + colL);
                f32x4 v = acc[m][n] + bv;
                const int off = (row * 512 + colL * 4) ^ ((row & 7) << 4);
                *(f32x4*)(smem + off) = v;
            }
        }
        __syncthreads();
        constexpr int ITER = TM / 8;
#pragma unroll
        for (int q = 0; q < ITER; ++q) {
            const int flat = q * 4096 + tid * 16;
            const int row = flat >> 9, cbyte = flat & 511;
            f32x4 v = *(const f32x4*)(smem + ((row * 512 + cbyte) ^ ((row & 7) << 4)));
            const long base = (brow + row) * 256 + bcol + (cbyte >> 2);
            f32x4 xo = *(const f32x4*)(Xf + base);
            f32x4 nx = xo + v;
            *(f32x4*)(Xf + base) = nx;
            uint2 p;
            p.x = (unsigned)f2b(nx[0]) | ((unsigned)f2b(nx[1]) << 16);
            p.y = (unsigned)f2b(nx[2]) | ((unsigned)f2b(nx[3]) << 16);
            *(uint2*)(Xb + base) = p;
        }
    }
}

// ==== full edge pipeline fused into the R8 streaming skeleton ====
// t = ssp(erbf @ W1T^T + b1) computed as a 64-wide slab per K-step of
// GEMM2 (t slab in LDS, recomputed per col-half); gate = t @ W2T^T;
// msg = (gate+b2)*nmsg[src]; segment-sum -> msumf atomics.
// tedg NEVER exists in HBM (saves 134 MB/layer HBM traffic + 1 dispatch).
__global__ __launch_bounds__(256)
void fused_me(const unsigned short* __restrict__ A,      // erbf TE x 64, CSR order
              const unsigned short* __restrict__ W1T,    // 256 x 64
              const float* __restrict__ b1,
              const unsigned short* __restrict__ W2T,    // 256 x 256
              const float* __restrict__ b2,
              const unsigned short* __restrict__ nmsgb,  // TN x 256 bf16
              const int* __restrict__ gsrcs,
              const int* __restrict__ dstn,
              float* __restrict__ msumf)                 // TN x 256 f32 (zeroed)
{
    constexpr int TM = 128, MR = 4, NR = 4;

    // [erbf 16K][t_slab 16K][Bs 16K] ; epilogue msg tile reuses first 32K
    __shared__ __align__(16) unsigned char smem[49152];
    __shared__ int sm_src[TM];
    __shared__ int sm_dst[TM];
    unsigned short* Ae = (unsigned short*)smem;            // 128 x 64 bf16
    unsigned char*  Ts = smem + 16384;                     // 128 x 64 bf16 (t slab)
    unsigned short* Bs = (unsigned short*)(smem + 32768);  // 128 x 64 bf16 (W2 slab)

    const int tid  = threadIdx.x;
    const int lane = tid & 63;
    const int w    = tid >> 6;
    const int wr   = w >> 1, wc = w & 1;
    const int r16  = lane & 15;
    const int kg   = lane >> 4;

    const long brow = (long)blockIdx.y * TM;
    const int  bcol = blockIdx.x * 128;

    const int lrow  = lane >> 3;
    const int lslot = lane & 7;

    // ---- prologue: stage erbf tile (16 x 1KB chunks) + indices ----
#pragma unroll
    for (int i = 0; i < 4; ++i) {
        const int cc   = w * 4 + i;
        const int srow = cc * 8 + lrow;
        const int kch  = lslot ^ (srow & 7);
        const unsigned short* gp = A + (brow + srow) * 64 + kch * 8;
        __builtin_amdgcn_global_load_lds(
            (const __attribute__((address_space(1))) void*)gp,
            (__attribute__((address_space(3))) void*)(Ae + cc * 512), 16, 0, 0);
    }
    if (tid < TM) {
        sm_src[tid] = gsrcs[brow + tid];
        sm_dst[tid] = dstn[brow + tid];
    }
    __syncthreads();   // erbf staged (vmcnt drain), indices visible

    // nmsg prefetch (registers; consumed only in epilogue)
    uint2 pre[MR][NR];
#pragma unroll
    for (int m = 0; m < MR; ++m) {
        const int row = wr * 64 + m * 16 + r16;
        const int src = sm_src[row];
#pragma unroll
        for (int n = 0; n < NR; ++n) {
            const int colL = wc * 64 + n * 16 + kg * 4;
            pre[m][n] = *(const uint2*)(nmsgb + ((long)src << 8) + bcol + colL);
        }
    }

    f32x4 acc[MR][NR];
#pragma unroll
    for (int m = 0; m < MR; ++m)
#pragma unroll
        for (int n = 0; n < NR; ++n) acc[m][n] = f32x4{0.f, 0.f, 0.f, 0.f};

    for (int kk = 0; kk < 4; ++kk) {
        // ---- GEMM1 slab kk: t[:, kk*64 .. +64) in registers ----
        // (reads erbf LDS only; R5-verified swapped layout: lane r16 = edge,
        //  kg*4+j = channel within 16-block)
        f32x4 acc1[2][4];
#pragma unroll
        for (int eh = 0; eh < 2; ++eh)
#pragma unroll
            for (int n = 0; n < 4; ++n) acc1[eh][n] = f32x4{0.f, 0.f, 0.f, 0.f};
#pragma unroll
        for (int kc = 0; kc < 2; ++kc) {
            bf16x8 af[2];
#pragma unroll
            for (int eh = 0; eh < 2; ++eh) {
                const int row = w * 32 + eh * 16 + r16;
                const int slot = (kc * 4 + kg) ^ (row & 7);
                af[eh] = *(const bf16x8*)(Ae + row * 64 + slot * 8);
            }
#pragma unroll
            for (int n = 0; n < 4; ++n) {
                bf16x8 wf = *(const bf16x8*)(W1T + (kk * 64 + n * 16 + r16) * 64 + kc * 32 + kg * 8);
                acc1[0][n] = __builtin_amdgcn_mfma_f32_16x16x32_bf16(wf, af[0], acc1[0][n], 0, 0, 0);
                acc1[1][n] = __builtin_amdgcn_mfma_f32_16x16x32_bf16(wf, af[1], acc1[1][n], 0, 0, 0);
            }
        }

        __syncthreads();   // previous GEMM2's Ts/Bs reads complete

        // ---- stage W2 slab kk (async; drains at next barrier) ----
#pragma unroll
        for (int i = 0; i < 4; ++i) {
            const int cc   = w * 4 + i;
            const int srow = cc * 8 + lrow;
            const int kch  = lslot ^ (srow & 7);
            const unsigned short* gp = W2T + (bcol + srow) * 256 + kk * 64 + kch * 8;
            __builtin_amdgcn_global_load_lds(
                (const __attribute__((address_space(1))) void*)gp,
                (__attribute__((address_space(3))) void*)(Bs + cc * 512), 16, 0, 0);
        }

        // ---- t slab -> LDS (bias + ssp, 8B packs, XOR swizzle) ----
#pragma unroll
        for (int eh = 0; eh < 2; ++eh) {
            const int row = w * 32 + eh * 16 + r16;
            const int swz = (row & 7) << 4;
#pragma unroll
            for (int n = 0; n < 4; ++n) {
                const int cl = n * 16 + kg * 4;             // channel in slab
                const f32x4 bv = *(const f32x4*)(b1 + kk * 64 + cl);
                uint2 p;
                p.x = (unsigned)f2b(sspf(acc1[eh][n][0] + bv[0])) |
                      ((unsigned)f2b(sspf(acc1[eh][n][1] + bv[1])) << 16);
                p.y = (unsigned)f2b(sspf(acc1[eh][n][2] + bv[2])) |
                      ((unsigned)f2b(sspf(acc1[eh][n][3] + bv[3])) << 16);
                *(uint2*)(Ts + ((row * 128 + cl * 2) ^ swz)) = p;
            }
        }
        __syncthreads();   // Ts visible + Bs staged (barrier's vmcnt drain)

        // ---- GEMM2 partial (K-step kk) ----
        bf16x8 a[MR][2], b[NR][2];
#pragma unroll
        for (int m = 0; m < MR; ++m) {
            const int row = wr * 64 + m * 16 + r16;
#pragma unroll
            for (int kc = 0; kc < 2; ++kc) {
                const int off = (row * 128 + (kc * 4 + kg) * 16) ^ ((row & 7) << 4);
                a[m][kc] = *(const bf16x8*)(Ts + off);
            }
        }
#pragma unroll
        for (int n = 0; n < NR; ++n) {
            const int row = wc * 64 + n * 16 + r16;
            const unsigned short* base = Bs + row * 64;
#pragma unroll
            for (int kc = 0; kc < 2; ++kc) {
                const int slot = (kc * 4 + kg) ^ (row & 7);
                b[n][kc] = *(const bf16x8*)(base + slot * 8);
            }
        }
#pragma unroll
        for (int kc = 0; kc < 2; ++kc)
#pragma unroll
            for (int m = 0; m < MR; ++m)
#pragma unroll
                for (int n = 0; n < NR; ++n)
                    acc[m][n] = __builtin_amdgcn_mfma_f32_16x16x32_bf16(
                        b[n][kc], a[m][kc], acc[m][n], 0, 0, 0);
    }

    __syncthreads();   // erbf/Ts dead -> msg tile (first 32KB)

    // epilogue A: msg = (gate + b2) * nmsg[src] -> bf16 LDS (swizzled)
#pragma unroll
    for (int m = 0; m < MR; ++m) {
        const int row = wr * 64 + m * 16 + r16;
#pragma unroll
        for (int n = 0; n < NR; ++n) {
            const int colL = wc * 64 + n * 16 + kg * 4;
            const f32x4 bv = *(const f32x4*)(b2 + bcol + colL);
            const uint2 nm = pre[m][n];
            float v0 = (acc[m][n][0] + bv[0]) * b2f((unsigned short)(nm.x & 0xffff));
            float v1 = (acc[m][n][1] + bv[1]) * b2f((unsigned short)(nm.x >> 16));
            float v2 = (acc[m][n][2] + bv[2]) * b2f((unsigned short)(nm.y & 0xffff));
            float v3 = (acc[m][n][3] + bv[3]) * b2f((unsigned short)(nm.y >> 16));
            uint2 p;
            p.x = (unsigned)f2b(v0) | ((unsigned)f2b(v1) << 16);
            p.y = (unsigned)f2b(v2) | ((unsigned)f2b(v3) << 16);
            const int off = (row * 256 + colL * 2) ^ ((row & 7) << 4);
            *(uint2*)(smem + off) = p;
        }
    }
    __syncthreads();

    // epilogue B: per-column segment scan over 64-row stripe + f32 atomics
    {
        const int colL = tid & 127;
        const int r0   = (tid >> 7) * 64;
        float sum = 0.f;
        int cur = sm_dst[r0];
        for (int r = r0; r < r0 + 64; ++r) {
            const int dn = sm_dst[r];
            if (dn != cur) {
                atomicAdd(&msumf[(long)cur * 256 + bcol + colL], sum);
                sum = 0.f;
                cur = dn;
            }
            const unsigned short u =
                *(const unsigned short*)(smem + ((r * 256 + colL * 2) ^ ((r & 7) << 4)));
            sum += b2f(u);
        }
        atomicAdd(&msumf[(long)cur * 256 + bcol + colL], sum);
    }
}

// ---------------- small kernels ----------------
__global__ void k_offsets(const int* __restrict__ num_nodes, int* __restrict__ off) {
    __shared__ int s[Bb];
    int t = threadIdx.x;
    s[t] = num_nodes[t];
    __syncthreads();
    for (int d = 1; d < Bb; d <<= 1) {
        int v = (t >= d) ? s[t - d] : 0;
        __syncthreads();
        s[t] += v;
        __syncthreads();
    }
    off[t + 1] = s[t];
    if (t == 0) off[0] = 0;
}

__global__ void k_edgeprep(const int* __restrict__ edges, const int* __restrict__ off,
                           int* __restrict__ gsrc, int* __restrict__ gdst, int* __restrict__ cnt) {
    int ge = blockIdx.x * 256 + threadIdx.x;
    if (ge >= TE) return;
    int b = ge >> 11;
    int o = off[b];
    gsrc[ge] = edges[ge * 2 + 0] + o;
    int d = edges[ge * 2 + 1] + o;
    gdst[ge] = d;
    atomicAdd(&cnt[d], 1);
}

__global__ void k_scan(const int* __restrict__ cnt, int* __restrict__ coff, int* __restrict__ pos) {
    __shared__ int part[1024];
    int t = threadIdx.x;
    int loc[8];
    int s = 0;
#pragma unroll
    for (int j = 0; j < 8; ++j) { loc[j] = cnt[t * 8 + j]; s += loc[j]; }
    part[t] = s;
    __syncthreads();
    for (int d = 1; d < 1024; d <<= 1) {
        int v = (t >= d) ? part[t - d] : 0;
        __syncthreads();
        part[t] += v;
        __syncthreads();
    }
    int base = part[t] - s;
#pragma unroll
    for (int j = 0; j < 8; ++j) {
        int idx = t * 8 + j;
        coff[idx] = base;
        pos[idx]  = base;
        base += loc[j];
    }
    if (t == 1023) coff[TN] = part[1023];
}

__global__ void k_fill(const int* __restrict__ gdst, const int* __restrict__ gsrc,
                       int* __restrict__ pos, int* __restrict__ eidl,
                       int* __restrict__ gsrcs, int* __restrict__ dstn) {
    int ge = blockIdx.x * 256 + threadIdx.x;
    if (ge >= TE) return;
    int d = gdst[ge];
    int p = atomicAdd(&pos[d], 1);
    eidl[p]  = ge;
    gsrcs[p] = gsrc[ge];
    dstn[p]  = d;
}

__global__ void k_rbf(const float* __restrict__ ef, const int* __restrict__ eidl,
                      unsigned short* __restrict__ erbf) {
    int gid = blockIdx.x * 256 + threadIdx.x;   // TE * 64
    int i = gid >> 6, k = gid & 63;
    int ge = eidl[i];
    float v = 0.f;
    if (k < EDGE) {
        float d = ef[ge];
        float t = d - 0.1f * (float)k;
        v = __expf(-50.f * t * t);
    }
    erbf[gid] = f2b(v);
}

__global__ void k_embed(const int* __restrict__ nodes, const float* __restrict__ embed,
                        float* __restrict__ x, unsigned short* __restrict__ xb) {
    int gid = blockIdx.x * 256 + threadIdx.x;
    int i = gid >> 8, c = gid & 255;
    float v = embed[(nodes[i] << 8) + c];
    x[gid] = v;
    xb[gid] = f2b(v);
}

__global__ void k_cvt(const float* __restrict__ f, unsigned short* __restrict__ b) {
    int gid = blockIdx.x * 256 + threadIdx.x;   // TN*256/4 threads
    f32x4 v = *(const f32x4*)(f + gid * 4);
    uint2 p;
    p.x = (unsigned)f2b(v[0]) | ((unsigned)f2b(v[1]) << 16);
    p.y = (unsigned)f2b(v[2]) | ((unsigned)f2b(v[3]) << 16);
    *(uint2*)(b + gid * 4) = p;
}

__global__ void k_wprep(const float* __restrict__ me_w1, const float* __restrict__ me_w2,
                        const float* __restrict__ mn_w1, const float* __restrict__ mn_w2,
                        const float* __restrict__ st_w1, const float* __restrict__ st_w2,
                        const float* __restrict__ ro_w1,
                        unsigned short* __restrict__ me1T, unsigned short* __restrict__ me2T,
                        unsigned short* __restrict__ mn1T, unsigned short* __restrict__ mn2T,
                        unsigned short* __restrict__ st1T, unsigned short* __restrict__ st2T,
                        unsigned short* __restrict__ ro1T) {
    int gid = blockIdx.x * 256 + threadIdx.x;
    const int S1 = Ll * 256 * EKPAD;
    if (gid < S1) {
        int i = gid / (256 * EKPAD);
        int r = gid % (256 * EKPAD);
        int n = r / EKPAD, k = r % EKPAD;
        float v = (k < EDGE) ? me_w1[(i * EDGE + k) * 256 + n] : 0.f;
        me1T[gid] = f2b(v);
        return;
    }
    gid -= S1;
    const int S2 = Ll * 256 * 256;
    const float* srcs[5] = { me_w2, mn_w1, mn_w2, st_w1, st_w2 };
    unsigned short* dsts[5] = { me2T, mn1T, mn2T, st1T, st2T };
#pragma unroll
    for (int q = 0; q < 5; ++q) {
        if (gid < S2) {
            int i = gid >> 16;
            int r = gid & 65535;
            int n = r >> 8, k = r & 255;
            dsts[q][gid] = f2b(srcs[q][(i << 16) + k * 256 + n]);
            return;
        }
        gid -= S2;
    }
    int n = gid >> 8, k = gid & 255;
    ro1T[gid] = f2b(ro_w1[k * 256 + n]);
}

__global__ void k_readout(const unsigned short* __restrict__ t, const float* __restrict__ w2,
                          const float* __restrict__ b2, const int* __restrict__ num_nodes,
                          const float* __restrict__ evw, const float* __restrict__ evb,
                          float* __restrict__ out) {
    __shared__ float red[256];
    int b = blockIdx.x, tid = threadIdx.x;
    const unsigned short* tb = t + (long)b * Nn * 256;
    float part = 0.f;
    for (int i = tid; i < Nn * 256; i += 256)
        part += b2f(tb[i]) * w2[i & 255];
    red[tid] = part;
    __syncthreads();
    for (int d = 128; d > 0; d >>= 1) {
        if (tid < d) red[tid] += red[tid + d];
        __syncthreads();
    }
    if (tid == 0) {
        float g = red[0] + (float)Nn * b2[0];
        g = g * 2.0f + (-1.5f) * (float)num_nodes[b];
        out[b * 4 + 0] = g * evw[0] + evb[0];
        out[b * 4 + 1] = spf(g * evw[1] + evb[1]);
        out[b * 4 + 2] = spf(g * evw[2] + evb[2]) + 1.f;
        out[b * 4 + 3] = spf(g * evw[3] + evb[3]);
    }
}

// ---------------- workspace layout ----------------
constexpr size_t al(size_t x) { return (x + 255) & ~(size_t)255; }
constexpr size_t O_OFF    = 0;
constexpr size_t O_GSRC   = al(O_OFF + 65 * 4);
constexpr size_t O_GDST   = al(O_GSRC + (size_t)TE * 4);
constexpr size_t O_CNT    = al(O_GDST + (size_t)TE * 4);
constexpr size_t O_COFF   = al(O_CNT + (size_t)TN * 4);
constexpr size_t O_POS    = al(O_COFF + (size_t)(TN + 1) * 4);
constexpr size_t O_EIDL   = al(O_POS + (size_t)TN * 4);
constexpr size_t O_GSRCS  = al(O_EIDL + (size_t)TE * 4);
constexpr size_t O_DSTN   = al(O_GSRCS + (size_t)TE * 4);
constexpr size_t O_ERBF   = al(O_DSTN + (size_t)TE * 4);
constexpr size_t O_ME1T   = al(O_ERBF + (size_t)TE * EKPAD * 2);
constexpr size_t O_ME2T   = al(O_ME1T + (size_t)Ll * 256 * EKPAD * 2);
constexpr size_t O_MN1T   = al(O_ME2T + (size_t)Ll * 256 * 256 * 2);
constexpr size_t O_MN2T   = al(O_MN1T + (size_t)Ll * 256 * 256 * 2);
constexpr size_t O_ST1T   = al(O_MN2T + (size_t)Ll * 256 * 256 * 2);
constexpr size_t O_ST2T   = al(O_ST1T + (size_t)Ll * 256 * 256 * 2);
constexpr size_t O_RO1T   = al(O_ST2T + (size_t)Ll * 256 * 256 * 2);
constexpr size_t O_X      = al(O_RO1T + (size_t)256 * 256 * 2);
constexpr size_t O_XB     = al(O_X + (size_t)TN * 256 * 4);
constexpr size_t O_TMPB   = al(O_XB + (size_t)TN * 256 * 2);
constexpr size_t O_NMSG   = al(O_TMPB + (size_t)TN * 256 * 2);
constexpr size_t O_MSUM   = al(O_NMSG + (size_t)TN * 256 * 2);
constexpr size_t O_MSUMF  = al(O_MSUM + (size_t)TN * 256 * 2);
constexpr size_t WS_NEED  = al(O_MSUMF + (size_t)TN * 256 * 4);

extern "C" void kernel_launch(void* const* d_in, const int* in_sizes, int n_in,
                              void* d_out, int out_size, void* d_ws, size_t ws_size,
                              hipStream_t stream) {
    if (ws_size < WS_NEED) return;

    const int*   nodes     = (const int*)d_in[0];
    const int*   num_nodes = (const int*)d_in[1];
    const int*   edges     = (const int*)d_in[2];
    const float* efeat     = (const float*)d_in[3];
    const float* embed     = (const float*)d_in[5];
    const float* me_w1 = (const float*)d_in[6],  *me_b1 = (const float*)d_in[7];
    const float* me_w2 = (const float*)d_in[8],  *me_b2 = (const float*)d_in[9];
    const float* mn_w1 = (const float*)d_in[10], *mn_b1 = (const float*)d_in[11];
    const float* mn_w2 = (const float*)d_in[12], *mn_b2 = (const float*)d_in[13];
    const float* st_w1 = (const float*)d_in[14], *st_b1 = (const float*)d_in[15];
    const float* st_w2 = (const float*)d_in[16], *st_b2 = (const float*)d_in[17];
    const float* ro_w1 = (const float*)d_in[18], *ro_b1 = (const float*)d_in[19];
    const float* ro_w2 = (const float*)d_in[20], *ro_b2 = (const float*)d_in[21];
    const float* ev_w  = (const float*)d_in[22], *ev_b  = (const float*)d_in[23];

    char* ws = (char*)d_ws;
    int* off   = (int*)(ws + O_OFF);
    int* gsrc  = (int*)(ws + O_GSRC);
    int* gdst  = (int*)(ws + O_GDST);
    int* cnt   = (int*)(ws + O_CNT);
    int* coff  = (int*)(ws + O_COFF);
    int* pos   = (int*)(ws + O_POS);
    int* eidl  = (int*)(ws + O_EIDL);
    int* gsrcs = (int*)(ws + O_GSRCS);
    int* dstn  = (int*)(ws + O_DSTN);
    unsigned short* erbf  = (unsigned short*)(ws + O_ERBF);
    unsigned short* me1T  = (unsigned short*)(ws + O_ME1T);
    unsigned short* me2T  = (unsigned short*)(ws + O_ME2T);
    unsigned short* mn1T  = (unsigned short*)(ws + O_MN1T);
    unsigned short* mn2T  = (unsigned short*)(ws + O_MN2T);
    unsigned short* st1T  = (unsigned short*)(ws + O_ST1T);
    unsigned short* st2T  = (unsigned short*)(ws + O_ST2T);
    unsigned short* ro1T  = (unsigned short*)(ws + O_RO1T);
    float*          x     = (float*)(ws + O_X);
    unsigned short* xb    = (unsigned short*)(ws + O_XB);
    unsigned short* tmpb  = (unsigned short*)(ws + O_TMPB);
    unsigned short* nmsgb = (unsigned short*)(ws + O_NMSG);
    unsigned short* msum  = (unsigned short*)(ws + O_MSUM);
    float*          msumf = (float*)(ws + O_MSUMF);
    float* out = (float*)d_out;

    hipMemsetAsync(cnt, 0, TN * 4, stream);
    k_offsets<<<1, Bb, 0, stream>>>(num_nodes, off);
    k_edgeprep<<<TE / 256, 256, 0, stream>>>(edges, off, gsrc, gdst, cnt);
    k_scan<<<1, 1024, 0, stream>>>(cnt, coff, pos);
    k_fill<<<TE / 256, 256, 0, stream>>>(gdst, gsrc, pos, eidl, gsrcs, dstn);
    k_rbf<<<(TE * EKPAD) / 256, 256, 0, stream>>>(efeat, eidl, erbf);
    k_embed<<<TN, 256, 0, stream>>>(nodes, embed, x, xb);
    {
        const int total = Ll * 256 * EKPAD + 5 * Ll * 256 * 256 + 256 * 256;
        k_wprep<<<total / 256, 256, 0, stream>>>(me_w1, me_w2, mn_w1, mn_w2, st_w1, st_w2, ro_w1,
                                                 me1T, me2T, mn1T, mn2T, st1T, st2T, ro1T);
    }

    const dim3 gE(2, TE / 128), gN(2, TN / 64), blk(256);
    for (int i = 0; i < Ll; ++i) {
        gemm_k<1, 0, 64><<<gN, blk, 0, stream>>>(xb, mn1T + i * 65536, mn_b1 + i * 256,
                                                 tmpb, nullptr, nullptr, TN, 256);
        gemm_k<0, 0, 64><<<gN, blk, 0, stream>>>(tmpb, mn2T + i * 65536, mn_b2 + i * 256,
                                                 nmsgb, nullptr, nullptr, TN, 256);
        hipMemsetAsync(msumf, 0, (size_t)TN * 256 * 4, stream);
        fused_me<<<gE, blk, 0, stream>>>(erbf, me1T + i * 256 * EKPAD, me_b1 + i * 256,
                                         me2T + i * 65536, me_b2 + i * 256,
                                         nmsgb, gsrcs, dstn, msumf);
        k_cvt<<<(TN * 256 / 4) / 256, 256, 0, stream>>>(msumf, msum);
        gemm_k<1, 0, 64><<<gN, blk, 0, stream>>>(msum, st1T + i * 65536, st_b1 + i * 256,
                                                 tmpb, nullptr, nullptr, TN, 256);
        gemm_k<0, 2, 64><<<gN, blk, 0, stream>>>(tmpb, st2T + i * 65536, st_b2 + i * 256,
                                                 nullptr, x, xb, TN, 256);
    }

    gemm_k<1, 0, 64><<<gN, blk, 0, stream>>>(xb, ro1T, ro_b1, tmpb, nullptr, nullptr, TN, 256);
    k_readout<<<Bb, 256, 0, stream>>>(tmpb, ro_w2, ro_b2, num_nodes, ev_w, ev_b, out);
}

// Round 11
// 523.239 us; speedup vs baseline: 2.6799x; 2.6799x over previous
//
#include <hip/hip_runtime.h>

#define Bb 64
#define Nn 128
#define Ee 2048
#define Hh 256
#define Ll 6
#define TN 8192
#define TE 131072
#define EDGE 50
#define EKPAD 64
#define TABN 4096
// grid spacing covers [0, CUTOFF]; i0+1 <= TABN-2 for d < 5.0
#define TSCALE ((float)(TABN - 2) / 5.0f)

typedef __attribute__((ext_vector_type(4))) float f32x4;
typedef __attribute__((ext_vector_type(8))) __bf16 bf16x8;
typedef __attribute__((ext_vector_type(8))) unsigned short ushort8;

__device__ inline float b2f(unsigned short u) {
    union { unsigned u; float f; } v; v.u = ((unsigned)u) << 16; return v.f;
}
__device__ inline unsigned short f2b(float f) {
    union { float f; unsigned u; } v; v.f = f;
    unsigned r = v.u + 0x7fffu + ((v.u >> 16) & 1u);
    return (unsigned short)(r >> 16);
}
__device__ inline float spf(float x) {
    return fmaxf(x, 0.f) + __logf(1.f + __expf(-fabsf(x)));
}
__device__ inline float sspf(float x) {
    return spf(x) - 0.69314718055994530942f;
}

// ---------------- GEMM (R4-verified): C = act(A @ WT^T + bias), N fixed 256 ----
template <int ACT, int OUTMODE, int TM>
__global__ __launch_bounds__(256)
void gemm_k(const unsigned short* __restrict__ A,
            const unsigned short* __restrict__ WT,
            const float* __restrict__ bias,
            unsigned short* __restrict__ Cb,
            float* __restrict__ Xf,
            unsigned short* __restrict__ Xb,
            int M, int K)
{
    constexpr int BK  = 64;
    constexpr int TNc = 128;
    constexpr int MR  = TM / 32;
    constexpr int NR  = 4;
    constexpr int STAGE_B = (TM + TNc) * BK * 2;
    constexpr int EPI_B   = (OUTMODE == 2) ? TM * TNc * 4 : TM * TNc * 2;
    constexpr int SMEM_B  = STAGE_B > EPI_B ? STAGE_B : EPI_B;

    __shared__ __align__(16) unsigned char smem[SMEM_B];
    unsigned short* As = (unsigned short*)smem;
    unsigned short* Bs = As + TM * BK;

    const int tid  = threadIdx.x;
    const int lane = tid & 63;
    const int w    = tid >> 6;
    const int wr   = w >> 1, wc = w & 1;
    const int r16  = lane & 15;
    const int kg   = lane >> 4;

    const long brow = (long)blockIdx.y * TM;
    const int  bcol = blockIdx.x * TNc;

    constexpr int ACH = TM / 8;
    constexpr int NCH = ACH + TNc / 8;
    constexpr int IPW = NCH / 4;
    const int lrow  = lane >> 3;
    const int lslot = lane & 7;

    f32x4 acc[MR][NR];
#pragma unroll
    for (int m = 0; m < MR; ++m)
#pragma unroll
        for (int n = 0; n < NR; ++n) acc[m][n] = f32x4{0.f, 0.f, 0.f, 0.f};

    for (int k0 = 0; k0 < K; k0 += BK) {
        __syncthreads();
#pragma unroll
        for (int i = 0; i < IPW; ++i) {
            const int c    = w * IPW + i;
            const bool isA = c < ACH;
            const int cc   = isA ? c : c - ACH;
            const int srow = cc * 8 + lrow;
            const int kch  = lslot ^ (srow & 7);
            const unsigned short* gp = isA
                ? A  + (brow + srow) * (long)K + k0 + kch * 8
                : WT + (bcol + srow) * (long)K + k0 + kch * 8;
            unsigned short* lp = (isA ? As : Bs) + cc * 512;
            __builtin_amdgcn_global_load_lds(
                (const __attribute__((address_space(1))) void*)gp,
                (__attribute__((address_space(3))) void*)lp, 16, 0, 0);
        }
        __syncthreads();

        bf16x8 a[MR][2], b[NR][2];
#pragma unroll
        for (int m = 0; m < MR; ++m) {
            const int row = wr * (MR * 16) + m * 16 + r16;
            const unsigned short* base = As + row * BK;
#pragma unroll
            for (int kk = 0; kk < 2; ++kk) {
                const int slot = (kk * 4 + kg) ^ (row & 7);
                a[m][kk] = *(const bf16x8*)(base + slot * 8);
            }
        }
#pragma unroll
        for (int n = 0; n < NR; ++n) {
            const int row = wc * 64 + n * 16 + r16;
            const unsigned short* base = Bs + row * BK;
#pragma unroll
            for (int kk = 0; kk < 2; ++kk) {
                const int slot = (kk * 4 + kg) ^ (row & 7);
                b[n][kk] = *(const bf16x8*)(base + slot * 8);
            }
        }
#pragma unroll
        for (int kk = 0; kk < 2; ++kk)
#pragma unroll
            for (int m = 0; m < MR; ++m)
#pragma unroll
                for (int n = 0; n < NR; ++n)
                    acc[m][n] = __builtin_amdgcn_mfma_f32_16x16x32_bf16(
                        b[n][kk], a[m][kk], acc[m][n], 0, 0, 0);
    }

    __syncthreads();

    if (OUTMODE != 2) {
#pragma unroll
        for (int m = 0; m < MR; ++m) {
            const int row = wr * (MR * 16) + m * 16 + r16;
#pragma unroll
            for (int n = 0; n < NR; ++n) {
                const int colL = wc * 64 + n * 16 + kg * 4;
                const f32x4 bv = *(const f32x4*)(bias + bcol + colL);
                float v0 = acc[m][n][0] + bv[0];
                float v1 = acc[m][n][1] + bv[1];
                float v2 = acc[m][n][2] + bv[2];
                float v3 = acc[m][n][3] + bv[3];
                if (ACT) { v0 = sspf(v0); v1 = sspf(v1); v2 = sspf(v2); v3 = sspf(v3); }
                uint2 p;
                p.x = (unsigned)f2b(v0) | ((unsigned)f2b(v1) << 16);
                p.y = (unsigned)f2b(v2) | ((unsigned)f2b(v3) << 16);
                const int off = (row * 256 + colL * 2) ^ ((row & 7) << 4);
                *(uint2*)(smem + off) = p;
            }
        }
        __syncthreads();
        constexpr int ITER = TM / 16;
#pragma unroll
        for (int q = 0; q < ITER; ++q) {
            const int flat = q * 4096 + tid * 16;
            const int row = flat >> 8, cbyte = flat & 255;
            uint4 d = *(const uint4*)(smem + ((row * 256 + cbyte) ^ ((row & 7) << 4)));
            *(uint4*)((unsigned char*)Cb + (brow + row) * 512 + bcol * 2 + cbyte) = d;
        }
    } else {
#pragma unroll
        for (int m = 0; m < MR; ++m) {
            const int row = wr * (MR * 16) + m * 16 + r16;
#pragma unroll
            for (int n = 0; n < NR; ++n) {
                const int colL = wc * 64 + n * 16 + kg * 4;
                const f32x4 bv = *(const f32x4*)(bias + bcol + colL);
                f32x4 v = acc[m][n] + bv;
                const int off = (row * 512 + colL * 4) ^ ((row & 7) << 4);
                *(f32x4*)(smem + off) = v;
            }
        }
        __syncthreads();
        constexpr int ITER = TM / 8;
#pragma unroll
        for (int q = 0; q < ITER; ++q) {
            const int flat = q * 4096 + tid * 16;
            const int row = flat >> 9, cbyte = flat & 511;
            f32x4 v = *(const f32x4*)(smem + ((row * 512 + cbyte) ^ ((row & 7) << 4)));
            const long base = (brow + row) * 256 + bcol + (cbyte >> 2);
            f32x4 xo = *(const f32x4*)(Xf + base);
            f32x4 nx = xo + v;
            *(f32x4*)(Xf + base) = nx;
            uint2 p;
            p.x = (unsigned)f2b(nx[0]) | ((unsigned)f2b(nx[1]) << 16);
            p.y = (unsigned)f2b(nx[2]) | ((unsigned)f2b(nx[3]) << 16);
            *(uint2*)(Xb + base) = p;
        }
    }
}

// ---------------- small kernels ----------------
__global__ void k_offsets(const int* __restrict__ num_nodes, int* __restrict__ off) {
    __shared__ int s[Bb];
    int t = threadIdx.x;
    s[t] = num_nodes[t];
    __syncthreads();
    for (int d = 1; d < Bb; d <<= 1) {
        int v = (t >= d) ? s[t - d] : 0;
        __syncthreads();
        s[t] += v;
        __syncthreads();
    }
    off[t + 1] = s[t];
    if (t == 0) off[0] = 0;
}

__global__ void k_edgeprep(const int* __restrict__ edges, const int* __restrict__ off,
                           int* __restrict__ gsrc, int* __restrict__ gdst, int* __restrict__ cnt) {
    int ge = blockIdx.x * 256 + threadIdx.x;
    if (ge >= TE) return;
    int b = ge >> 11;
    int o = off[b];
    gsrc[ge] = edges[ge * 2 + 0] + o;
    int d = edges[ge * 2 + 1] + o;
    gdst[ge] = d;
    atomicAdd(&cnt[d], 1);
}

__global__ void k_scan(const int* __restrict__ cnt, int* __restrict__ coff, int* __restrict__ pos) {
    __shared__ int part[1024];
    int t = threadIdx.x;
    int loc[8];
    int s = 0;
#pragma unroll
    for (int j = 0; j < 8; ++j) { loc[j] = cnt[t * 8 + j]; s += loc[j]; }
    part[t] = s;
    __syncthreads();
    for (int d = 1; d < 1024; d <<= 1) {
        int v = (t >= d) ? part[t - d] : 0;
        __syncthreads();
        part[t] += v;
        __syncthreads();
    }
    int base = part[t] - s;
#pragma unroll
    for (int j = 0; j < 8; ++j) {
        int idx = t * 8 + j;
        coff[idx] = base;
        pos[idx]  = base;
        base += loc[j];
    }
    if (t == 1023) coff[TN] = part[1023];
}

// CSR fill: per-edge src id and raw distance in CSR (dst-grouped) order
__global__ void k_fill(const int* __restrict__ gdst, const int* __restrict__ gsrc,
                       const float* __restrict__ ef,
                       int* __restrict__ pos, int* __restrict__ gsrcs,
                       float* __restrict__ dcsr) {
    int ge = blockIdx.x * 256 + threadIdx.x;
    if (ge >= TE) return;
    int d = gdst[ge];
    int p = atomicAdd(&pos[d], 1);
    gsrcs[p] = gsrc[ge];
    dcsr[p]  = ef[ge];
}

// RBF evaluated on the TABN-point d-grid (input for table-building GEMMs)
__global__ void k_rbfgrid(unsigned short* __restrict__ rbfg) {
    int gid = blockIdx.x * 256 + threadIdx.x;   // TABN * 64
    int i = gid >> 6, k = gid & 63;
    float v = 0.f;
    if (k < EDGE) {
        float d = (float)i / TSCALE;
        float t = d - 0.1f * (float)k;
        v = __expf(-50.f * t * t);
    }
    rbfg[gid] = f2b(v);
}

__global__ void k_embed(const int* __restrict__ nodes, const float* __restrict__ embed,
                        float* __restrict__ x, unsigned short* __restrict__ xb) {
    int gid = blockIdx.x * 256 + threadIdx.x;
    int i = gid >> 8, c = gid & 255;
    float v = embed[(nodes[i] << 8) + c];
    x[gid] = v;
    xb[gid] = f2b(v);
}

__global__ void k_wprep(const float* __restrict__ me_w1, const float* __restrict__ me_w2,
                        const float* __restrict__ mn_w1, const float* __restrict__ mn_w2,
                        const float* __restrict__ st_w1, const float* __restrict__ st_w2,
                        const float* __restrict__ ro_w1,
                        unsigned short* __restrict__ me1T, unsigned short* __restrict__ me2T,
                        unsigned short* __restrict__ mn1T, unsigned short* __restrict__ mn2T,
                        unsigned short* __restrict__ st1T, unsigned short* __restrict__ st2T,
                        unsigned short* __restrict__ ro1T) {
    int gid = blockIdx.x * 256 + threadIdx.x;
    const int S1 = Ll * 256 * EKPAD;
    if (gid < S1) {
        int i = gid / (256 * EKPAD);
        int r = gid % (256 * EKPAD);
        int n = r / EKPAD, k = r % EKPAD;
        float v = (k < EDGE) ? me_w1[(i * EDGE + k) * 256 + n] : 0.f;
        me1T[gid] = f2b(v);
        return;
    }
    gid -= S1;
    const int S2 = Ll * 256 * 256;
    const float* srcs[5] = { me_w2, mn_w1, mn_w2, st_w1, st_w2 };
    unsigned short* dsts[5] = { me2T, mn1T, mn2T, st1T, st2T };
#pragma unroll
    for (int q = 0; q < 5; ++q) {
        if (gid < S2) {
            int i = gid >> 16;
            int r = gid & 65535;
            int n = r >> 8, k = r & 255;
            dsts[q][gid] = f2b(srcs[q][(i << 16) + k * 256 + n]);
            return;
        }
        gid -= S2;
    }
    int n = gid >> 8, k = gid & 255;
    ro1T[gid] = f2b(ro_w1[k * 256 + n]);
}

// edge aggregation via gate-table lookup + lerp (table L2-resident):
// msum[n][c] = sum_{edges e->n} lerp(tab[i0(d_e)][c], tab[i0+1][c]) * nmsg[src_e][c]
// 8 nodes/block, 32 lanes/node, 8 channels/lane; per-node ownership -> no atomics.
__global__ void k_aggtab(const float* __restrict__ dcsr,
                         const unsigned short* __restrict__ tab,     // TABN x 256 (layer)
                         const unsigned short* __restrict__ nmsgb,
                         const int* __restrict__ coff,
                         const int* __restrict__ gsrcs,
                         unsigned short* __restrict__ msum) {
    int tid = threadIdx.x;
    int which = tid >> 5, local = tid & 31;
    int n = blockIdx.x * 8 + which;
    int c0 = local * 8;
    float s0 = 0.f, s1 = 0.f, s2 = 0.f, s3 = 0.f, s4 = 0.f, s5 = 0.f, s6 = 0.f, s7 = 0.f;
    int beg = coff[n], end = coff[n + 1];
    for (int i = beg; i < end; ++i) {
        float d  = dcsr[i];
        int   sr = gsrcs[i];
        float xx = d * TSCALE;
        int   i0 = (int)xx;
        float f  = xx - (float)i0;
        ushort8 g0 = *(const ushort8*)(tab + (long)i0 * 256 + c0);
        ushort8 g1 = *(const ushort8*)(tab + (long)(i0 + 1) * 256 + c0);
        ushort8 nm = *(const ushort8*)(nmsgb + ((long)sr << 8) + c0);
        float a0 = b2f(g0[0]), a1 = b2f(g0[1]), a2 = b2f(g0[2]), a3 = b2f(g0[3]);
        float a4 = b2f(g0[4]), a5 = b2f(g0[5]), a6 = b2f(g0[6]), a7 = b2f(g0[7]);
        s0 += (a0 + (b2f(g1[0]) - a0) * f) * b2f(nm[0]);
        s1 += (a1 + (b2f(g1[1]) - a1) * f) * b2f(nm[1]);
        s2 += (a2 + (b2f(g1[2]) - a2) * f) * b2f(nm[2]);
        s3 += (a3 + (b2f(g1[3]) - a3) * f) * b2f(nm[3]);
        s4 += (a4 + (b2f(g1[4]) - a4) * f) * b2f(nm[4]);
        s5 += (a5 + (b2f(g1[5]) - a5) * f) * b2f(nm[5]);
        s6 += (a6 + (b2f(g1[6]) - a6) * f) * b2f(nm[6]);
        s7 += (a7 + (b2f(g1[7]) - a7) * f) * b2f(nm[7]);
    }
    ushort8 o;
    o[0] = f2b(s0); o[1] = f2b(s1); o[2] = f2b(s2); o[3] = f2b(s3);
    o[4] = f2b(s4); o[5] = f2b(s5); o[6] = f2b(s6); o[7] = f2b(s7);
    *(ushort8*)(msum + ((long)n << 8) + c0) = o;
}

__global__ void k_readout(const unsigned short* __restrict__ t, const float* __restrict__ w2,
                          const float* __restrict__ b2, const int* __restrict__ num_nodes,
                          const float* __restrict__ evw, const float* __restrict__ evb,
                          float* __restrict__ out) {
    __shared__ float red[256];
    int b = blockIdx.x, tid = threadIdx.x;
    const unsigned short* tb = t + (long)b * Nn * 256;
    float part = 0.f;
    for (int i = tid; i < Nn * 256; i += 256)
        part += b2f(tb[i]) * w2[i & 255];
    red[tid] = part;
    __syncthreads();
    for (int d = 128; d > 0; d >>= 1) {
        if (tid < d) red[tid] += red[tid + d];
        __syncthreads();
    }
    if (tid == 0) {
        float g = red[0] + (float)Nn * b2[0];
        g = g * 2.0f + (-1.5f) * (float)num_nodes[b];
        out[b * 4 + 0] = g * evw[0] + evb[0];
        out[b * 4 + 1] = spf(g * evw[1] + evb[1]);
        out[b * 4 + 2] = spf(g * evw[2] + evb[2]) + 1.f;
        out[b * 4 + 3] = spf(g * evw[3] + evb[3]);
    }
}

// ---------------- workspace layout ----------------
constexpr size_t al(size_t x) { return (x + 255) & ~(size_t)255; }
constexpr size_t O_OFF    = 0;
constexpr size_t O_GSRC   = al(O_OFF + 65 * 4);
constexpr size_t O_GDST   = al(O_GSRC + (size_t)TE * 4);
constexpr size_t O_CNT    = al(O_GDST + (size_t)TE * 4);
constexpr size_t O_COFF   = al(O_CNT + (size_t)TN * 4);
constexpr size_t O_POS    = al(O_COFF + (size_t)(TN + 1) * 4);
constexpr size_t O_GSRCS  = al(O_POS + (size_t)TN * 4);
constexpr size_t O_DCSR   = al(O_GSRCS + (size_t)TE * 4);
constexpr size_t O_RBFG   = al(O_DCSR + (size_t)TE * 4);
constexpr size_t O_TTAB   = al(O_RBFG + (size_t)TABN * EKPAD * 2);
constexpr size_t O_GTAB   = al(O_TTAB + (size_t)TABN * 256 * 2);
constexpr size_t O_ME1T   = al(O_GTAB + (size_t)Ll * TABN * 256 * 2);
constexpr size_t O_ME2T   = al(O_ME1T + (size_t)Ll * 256 * EKPAD * 2);
constexpr size_t O_MN1T   = al(O_ME2T + (size_t)Ll * 256 * 256 * 2);
constexpr size_t O_MN2T   = al(O_MN1T + (size_t)Ll * 256 * 256 * 2);
constexpr size_t O_ST1T   = al(O_MN2T + (size_t)Ll * 256 * 256 * 2);
constexpr size_t O_ST2T   = al(O_ST1T + (size_t)Ll * 256 * 256 * 2);
constexpr size_t O_RO1T   = al(O_ST2T + (size_t)Ll * 256 * 256 * 2);
constexpr size_t O_X      = al(O_RO1T + (size_t)256 * 256 * 2);
constexpr size_t O_XB     = al(O_X + (size_t)TN * 256 * 4);
constexpr size_t O_TMPB   = al(O_XB + (size_t)TN * 256 * 2);
constexpr size_t O_NMSG   = al(O_TMPB + (size_t)TN * 256 * 2);
constexpr size_t O_MSUM   = al(O_NMSG + (size_t)TN * 256 * 2);
constexpr size_t WS_NEED  = al(O_MSUM + (size_t)TN * 256 * 2);

extern "C" void kernel_launch(void* const* d_in, const int* in_sizes, int n_in,
                              void* d_out, int out_size, void* d_ws, size_t ws_size,
                              hipStream_t stream) {
    if (ws_size < WS_NEED) return;

    const int*   nodes     = (const int*)d_in[0];
    const int*   num_nodes = (const int*)d_in[1];
    const int*   edges     = (const int*)d_in[2];
    const float* efeat     = (const float*)d_in[3];
    const float* embed     = (const float*)d_in[5];
    const float* me_w1 = (const float*)d_in[6],  *me_b1 = (const float*)d_in[7];
    const float* me_w2 = (const float*)d_in[8],  *me_b2 = (const float*)d_in[9];
    const float* mn_w1 = (const float*)d_in[10], *mn_b1 = (const float*)d_in[11];
    const float* mn_w2 = (const float*)d_in[12], *mn_b2 = (const float*)d_in[13];
    const float* st_w1 = (const float*)d_in[14], *st_b1 = (const float*)d_in[15];
    const float* st_w2 = (const float*)d_in[16], *st_b2 = (const float*)d_in[17];
    const float* ro_w1 = (const float*)d_in[18], *ro_b1 = (const float*)d_in[19];
    const float* ro_w2 = (const float*)d_in[20], *ro_b2 = (const float*)d_in[21];
    const float* ev_w  = (const float*)d_in[22], *ev_b  = (const float*)d_in[23];

    char* ws = (char*)d_ws;
    int* off   = (int*)(ws + O_OFF);
    int* gsrc  = (int*)(ws + O_GSRC);
    int* gdst  = (int*)(ws + O_GDST);
    int* cnt   = (int*)(ws + O_CNT);
    int* coff  = (int*)(ws + O_COFF);
    int* pos   = (int*)(ws + O_POS);
    int* gsrcs = (int*)(ws + O_GSRCS);
    float* dcsr = (float*)(ws + O_DCSR);
    unsigned short* rbfg  = (unsigned short*)(ws + O_RBFG);
    unsigned short* ttab  = (unsigned short*)(ws + O_TTAB);
    unsigned short* gtab  = (unsigned short*)(ws + O_GTAB);
    unsigned short* me1T  = (unsigned short*)(ws + O_ME1T);
    unsigned short* me2T  = (unsigned short*)(ws + O_ME2T);
    unsigned short* mn1T  = (unsigned short*)(ws + O_MN1T);
    unsigned short* mn2T  = (unsigned short*)(ws + O_MN2T);
    unsigned short* st1T  = (unsigned short*)(ws + O_ST1T);
    unsigned short* st2T  = (unsigned short*)(ws + O_ST2T);
    unsigned short* ro1T  = (unsigned short*)(ws + O_RO1T);
    float*          x     = (float*)(ws + O_X);
    unsigned short* xb    = (unsigned short*)(ws + O_XB);
    unsigned short* tmpb  = (unsigned short*)(ws + O_TMPB);
    unsigned short* nmsgb = (unsigned short*)(ws + O_NMSG);
    unsigned short* msum  = (unsigned short*)(ws + O_MSUM);
    float* out = (float*)d_out;

    hipMemsetAsync(cnt, 0, TN * 4, stream);
    k_offsets<<<1, Bb, 0, stream>>>(num_nodes, off);
    k_edgeprep<<<TE / 256, 256, 0, stream>>>(edges, off, gsrc, gdst, cnt);
    k_scan<<<1, 1024, 0, stream>>>(cnt, coff, pos);
    k_fill<<<TE / 256, 256, 0, stream>>>(gdst, gsrc, efeat, pos, gsrcs, dcsr);
    k_rbfgrid<<<(TABN * EKPAD) / 256, 256, 0, stream>>>(rbfg);
    k_embed<<<TN, 256, 0, stream>>>(nodes, embed, x, xb);
    {
        const int total = Ll * 256 * EKPAD + 5 * Ll * 256 * 256 + 256 * 256;
        k_wprep<<<total / 256, 256, 0, stream>>>(me_w1, me_w2, mn_w1, mn_w2, st_w1, st_w2, ro_w1,
                                                 me1T, me2T, mn1T, mn2T, st1T, st2T, ro1T);
    }

    // ---- build per-layer gate tables: gtab[i] = ssp(rbfg@W1+b1)@W2+b2 ----
    const dim3 gT(2, TABN / 128), gN(2, TN / 64), blk(256);
    for (int i = 0; i < Ll; ++i) {
        gemm_k<1, 0, 128><<<gT, blk, 0, stream>>>(rbfg, me1T + i * 256 * EKPAD, me_b1 + i * 256,
                                                  ttab, nullptr, nullptr, TABN, EKPAD);
        gemm_k<0, 0, 128><<<gT, blk, 0, stream>>>(ttab, me2T + i * 65536, me_b2 + i * 256,
                                                  gtab + (size_t)i * TABN * 256, nullptr, nullptr,
                                                  TABN, 256);
    }

    for (int i = 0; i < Ll; ++i) {
        gemm_k<1, 0, 64><<<gN, blk, 0, stream>>>(xb, mn1T + i * 65536, mn_b1 + i * 256,
                                                 tmpb, nullptr, nullptr, TN, 256);
        gemm_k<0, 0, 64><<<gN, blk, 0, stream>>>(tmpb, mn2T + i * 65536, mn_b2 + i * 256,
                                                 nmsgb, nullptr, nullptr, TN, 256);
        k_aggtab<<<TN / 8, 256, 0, stream>>>(dcsr, gtab + (size_t)i * TABN * 256,
                                             nmsgb, coff, gsrcs, msum);
        gemm_k<1, 0, 64><<<gN, blk, 0, stream>>>(msum, st1T + i * 65536, st_b1 + i * 256,
                                                 tmpb, nullptr, nullptr, TN, 256);
        gemm_k<0, 2, 64><<<gN, blk, 0, stream>>>(tmpb, st2T + i * 65536, st_b2 + i * 256,
                                                 nullptr, x, xb, TN, 256);
    }

    gemm_k<1, 0, 64><<<gN, blk, 0, stream>>>(xb, ro1T, ro_b1, tmpb, nullptr, nullptr, TN, 256);
    k_readout<<<Bb, 256, 0, stream>>>(tmpb, ro_w2, ro_b2, num_nodes, ev_w, ev_b, out);
}

// Round 12
// 513.525 us; speedup vs baseline: 2.7306x; 1.0189x over previous
//
#include <hip/hip_runtime.h>

#define Bb 64
#define Nn 128
#define Ee 2048
#define Hh 256
#define Ll 6
#define TN 8192
#define TE 131072
#define EDGE 50
#define EKPAD 64
#define TABN 4096
#define TSCALE ((float)(TABN - 2) / 5.0f)

typedef __attribute__((ext_vector_type(4))) float f32x4;
typedef __attribute__((ext_vector_type(8))) __bf16 bf16x8;
typedef __attribute__((ext_vector_type(8))) unsigned short ushort8;

__device__ inline float b2f(unsigned short u) {
    union { unsigned u; float f; } v; v.u = ((unsigned)u) << 16; return v.f;
}
__device__ inline unsigned short f2b(float f) {
    union { float f; unsigned u; } v; v.f = f;
    unsigned r = v.u + 0x7fffu + ((v.u >> 16) & 1u);
    return (unsigned short)(r >> 16);
}
__device__ inline float spf(float x) {
    return fmaxf(x, 0.f) + __logf(1.f + __expf(-fabsf(x)));
}
__device__ inline float sspf(float x) {
    return spf(x) - 0.69314718055994530942f;
}

// ---------------- GEMM (R4-verified) + z-batch strides ----------------
// C = act(A @ WT^T + bias), N fixed 256. blockIdx.z selects a batch slice via
// the A/W/bias/C strides (0 strides + gridDim.z==1 reproduce the verified R4 path).
template <int ACT, int OUTMODE, int TM>
__global__ __launch_bounds__(256)
void gemm_k(const unsigned short* __restrict__ A,
            const unsigned short* __restrict__ WT,
            const float* __restrict__ bias,
            unsigned short* __restrict__ Cb,
            float* __restrict__ Xf,
            unsigned short* __restrict__ Xb,
            int M, int K,
            long Az, long Wz, long bz, long Cz)
{
    constexpr int BK  = 64;
    constexpr int TNc = 128;
    constexpr int MR  = TM / 32;
    constexpr int NR  = 4;
    constexpr int STAGE_B = (TM + TNc) * BK * 2;
    constexpr int EPI_B   = (OUTMODE == 2) ? TM * TNc * 4 : TM * TNc * 2;
    constexpr int SMEM_B  = STAGE_B > EPI_B ? STAGE_B : EPI_B;

    __shared__ __align__(16) unsigned char smem[SMEM_B];
    unsigned short* As = (unsigned short*)smem;
    unsigned short* Bs = As + TM * BK;

    const int z = blockIdx.z;
    A += z * Az; WT += z * Wz; bias += z * bz;
    if (Cb) Cb += z * Cz;

    const int tid  = threadIdx.x;
    const int lane = tid & 63;
    const int w    = tid >> 6;
    const int wr   = w >> 1, wc = w & 1;
    const int r16  = lane & 15;
    const int kg   = lane >> 4;

    const long brow = (long)blockIdx.y * TM;
    const int  bcol = blockIdx.x * TNc;

    constexpr int ACH = TM / 8;
    constexpr int NCH = ACH + TNc / 8;
    constexpr int IPW = NCH / 4;
    const int lrow  = lane >> 3;
    const int lslot = lane & 7;

    f32x4 acc[MR][NR];
#pragma unroll
    for (int m = 0; m < MR; ++m)
#pragma unroll
        for (int n = 0; n < NR; ++n) acc[m][n] = f32x4{0.f, 0.f, 0.f, 0.f};

    for (int k0 = 0; k0 < K; k0 += BK) {
        __syncthreads();
#pragma unroll
        for (int i = 0; i < IPW; ++i) {
            const int c    = w * IPW + i;
            const bool isA = c < ACH;
            const int cc   = isA ? c : c - ACH;
            const int srow = cc * 8 + lrow;
            const int kch  = lslot ^ (srow & 7);
            const unsigned short* gp = isA
                ? A  + (brow + srow) * (long)K + k0 + kch * 8
                : WT + (bcol + srow) * (long)K + k0 + kch * 8;
            unsigned short* lp = (isA ? As : Bs) + cc * 512;
            __builtin_amdgcn_global_load_lds(
                (const __attribute__((address_space(1))) void*)gp,
                (__attribute__((address_space(3))) void*)lp, 16, 0, 0);
        }
        __syncthreads();

        bf16x8 a[MR][2], b[NR][2];
#pragma unroll
        for (int m = 0; m < MR; ++m) {
            const int row = wr * (MR * 16) + m * 16 + r16;
            const unsigned short* base = As + row * BK;
#pragma unroll
            for (int kk = 0; kk < 2; ++kk) {
                const int slot = (kk * 4 + kg) ^ (row & 7);
                a[m][kk] = *(const bf16x8*)(base + slot * 8);
            }
        }
#pragma unroll
        for (int n = 0; n < NR; ++n) {
            const int row = wc * 64 + n * 16 + r16;
            const unsigned short* base = Bs + row * BK;
#pragma unroll
            for (int kk = 0; kk < 2; ++kk) {
                const int slot = (kk * 4 + kg) ^ (row & 7);
                b[n][kk] = *(const bf16x8*)(base + slot * 8);
            }
        }
#pragma unroll
        for (int kk = 0; kk < 2; ++kk)
#pragma unroll
            for (int m = 0; m < MR; ++m)
#pragma unroll
                for (int n = 0; n < NR; ++n)
                    acc[m][n] = __builtin_amdgcn_mfma_f32_16x16x32_bf16(
                        b[n][kk], a[m][kk], acc[m][n], 0, 0, 0);
    }

    __syncthreads();

    if (OUTMODE != 2) {
#pragma unroll
        for (int m = 0; m < MR; ++m) {
            const int row = wr * (MR * 16) + m * 16 + r16;
#pragma unroll
            for (int n = 0; n < NR; ++n) {
                const int colL = wc * 64 + n * 16 + kg * 4;
                const f32x4 bv = *(const f32x4*)(bias + bcol + colL);
                float v0 = acc[m][n][0] + bv[0];
                float v1 = acc[m][n][1] + bv[1];
                float v2 = acc[m][n][2] + bv[2];
                float v3 = acc[m][n][3] + bv[3];
                if (ACT) { v0 = sspf(v0); v1 = sspf(v1); v2 = sspf(v2); v3 = sspf(v3); }
                uint2 p;
                p.x = (unsigned)f2b(v0) | ((unsigned)f2b(v1) << 16);
                p.y = (unsigned)f2b(v2) | ((unsigned)f2b(v3) << 16);
                const int off = (row * 256 + colL * 2) ^ ((row & 7) << 4);
                *(uint2*)(smem + off) = p;
            }
        }
        __syncthreads();
        constexpr int ITER = TM / 16;
#pragma unroll
        for (int q = 0; q < ITER; ++q) {
            const int flat = q * 4096 + tid * 16;
            const int row = flat >> 8, cbyte = flat & 255;
            uint4 d = *(const uint4*)(smem + ((row * 256 + cbyte) ^ ((row & 7) << 4)));
            *(uint4*)((unsigned char*)Cb + (brow + row) * 512 + bcol * 2 + cbyte) = d;
        }
    } else {
#pragma unroll
        for (int m = 0; m < MR; ++m) {
            const int row = wr * (MR * 16) + m * 16 + r16;
#pragma unroll
            for (int n = 0; n < NR; ++n) {
                const int colL = wc * 64 + n * 16 + kg * 4;
                const f32x4 bv = *(const f32x4*)(bias + bcol + colL);
                f32x4 v = acc[m][n] + bv;
                const int off = (row * 512 + colL * 4) ^ ((row & 7) << 4);
                *(f32x4*)(smem + off) = v;
            }
        }
        __syncthreads();
        constexpr int ITER = TM / 8;
#pragma unroll
        for (int q = 0; q < ITER; ++q) {
            const int flat = q * 4096 + tid * 16;
            const int row = flat >> 9, cbyte = flat & 511;
            f32x4 v = *(const f32x4*)(smem + ((row * 512 + cbyte) ^ ((row & 7) << 4)));
            const long base = (brow + row) * 256 + bcol + (cbyte >> 2);
            f32x4 xo = *(const f32x4*)(Xf + base);
            f32x4 nx = xo + v;
            *(f32x4*)(Xf + base) = nx;
            uint2 p;
            p.x = (unsigned)f2b(nx[0]) | ((unsigned)f2b(nx[1]) << 16);
            p.y = (unsigned)f2b(nx[2]) | ((unsigned)f2b(nx[3]) << 16);
            *(uint2*)(Xb + base) = p;
        }
    }
}

// ============ fused node MLP (R7-verified structure): 32-row tiles ============
// out = [ssp(A @ W1T^T + b1)] @ W2T^T + b2 ; K=256 both GEMMs; W from L2.
// OUTMODE 0: Cb = bf16 result. 2: Xf += v; Xb = f2b(Xf).
template <int OUTMODE>
__global__ __launch_bounds__(256, 2)
void fused_node(const unsigned short* __restrict__ Ab,
                const unsigned short* __restrict__ W1T,
                const float* __restrict__ b1,
                const unsigned short* __restrict__ W2T,
                const float* __restrict__ b2,
                unsigned short* __restrict__ Cb,
                float* __restrict__ Xf,
                unsigned short* __restrict__ Xb)
{
    __shared__ __align__(16) unsigned char smem[32 * 1024];   // A(16K) + t(16K)
    unsigned short* A_lds = (unsigned short*)smem;            // 32 x 256 bf16
    unsigned char*  t_lds = smem + 16384;

    const int tid  = threadIdx.x;
    const int lane = tid & 63;
    const int w    = tid >> 6;
    const int rh   = w >> 1, ch = w & 1;      // quadrant: 16 rows x 128 cols
    const int r16  = lane & 15;
    const int kg   = lane >> 4;
    const long brow = (long)blockIdx.x * 32;

    // ---- stage A (16 chunks of 1KB = 2 rows each) ----
    {
        const int lrow  = lane >> 5;
        const int lslot = lane & 31;
#pragma unroll
        for (int i = 0; i < 4; ++i) {
            const int cc   = w * 4 + i;
            const int srow = cc * 2 + lrow;
            const int kch  = lslot ^ (srow & 7);
            const unsigned short* gp = Ab + (brow + srow) * 256 + kch * 8;
            __builtin_amdgcn_global_load_lds(
                (const __attribute__((address_space(1))) void*)gp,
                (__attribute__((address_space(3))) void*)(A_lds + cc * 512), 16, 0, 0);
        }
    }
    __syncthreads();

    const int arow = rh * 16 + r16;
    const int swz  = (arow & 7) << 4;

    // ---- GEMM1 ----
    f32x4 acc1[8];
#pragma unroll
    for (int n = 0; n < 8; ++n) acc1[n] = f32x4{0.f, 0.f, 0.f, 0.f};
#pragma unroll
    for (int kk = 0; kk < 8; ++kk) {
        const int slot = (kk * 4 + kg) ^ (arow & 7);
        bf16x8 af = *(const bf16x8*)(A_lds + arow * 256 + slot * 8);
#pragma unroll
        for (int n = 0; n < 8; ++n) {
            const int col = ch * 128 + n * 16 + r16;
            bf16x8 wf = *(const bf16x8*)(W1T + col * 256 + kk * 32 + kg * 8);
            acc1[n] = __builtin_amdgcn_mfma_f32_16x16x32_bf16(wf, af, acc1[n], 0, 0, 0);
        }
    }
#pragma unroll
    for (int n = 0; n < 8; ++n) {
        const int c0 = ch * 128 + n * 16 + kg * 4;
        const f32x4 bv = *(const f32x4*)(b1 + c0);
        uint2 p;
        p.x = (unsigned)f2b(sspf(acc1[n][0] + bv[0])) |
              ((unsigned)f2b(sspf(acc1[n][1] + bv[1])) << 16);
        p.y = (unsigned)f2b(sspf(acc1[n][2] + bv[2])) |
              ((unsigned)f2b(sspf(acc1[n][3] + bv[3])) << 16);
        *(uint2*)(t_lds + ((arow * 512 + c0 * 2) ^ swz)) = p;
    }
    __syncthreads();

    // ---- GEMM2 ----
    f32x4 acc2[8];
#pragma unroll
    for (int n = 0; n < 8; ++n) acc2[n] = f32x4{0.f, 0.f, 0.f, 0.f};
#pragma unroll
    for (int kk = 0; kk < 8; ++kk) {
        bf16x8 af = *(const bf16x8*)(t_lds + ((arow * 512 + kk * 64 + kg * 16) ^ swz));
#pragma unroll
        for (int n = 0; n < 8; ++n) {
            const int col = ch * 128 + n * 16 + r16;
            bf16x8 wf = *(const bf16x8*)(W2T + col * 256 + kk * 32 + kg * 8);
            acc2[n] = __builtin_amdgcn_mfma_f32_16x16x32_bf16(wf, af, acc2[n], 0, 0, 0);
        }
    }
    __syncthreads();   // A,t dead -> epilogue tile

    if (OUTMODE == 0) {
#pragma unroll
        for (int n = 0; n < 8; ++n) {
            const int c0 = ch * 128 + n * 16 + kg * 4;
            const f32x4 bv = *(const f32x4*)(b2 + c0);
            uint2 p;
            p.x = (unsigned)f2b(acc2[n][0] + bv[0]) | ((unsigned)f2b(acc2[n][1] + bv[1]) << 16);
            p.y = (unsigned)f2b(acc2[n][2] + bv[2]) | ((unsigned)f2b(acc2[n][3] + bv[3]) << 16);
            *(uint2*)(smem + ((arow * 512 + c0 * 2) ^ swz)) = p;
        }
        __syncthreads();
#pragma unroll
        for (int q = 0; q < 4; ++q) {
            const int flat = q * 4096 + tid * 16;
            const int row = flat >> 9, cbyte = flat & 511;
            uint4 d = *(const uint4*)(smem + ((row * 512 + cbyte) ^ ((row & 7) << 4)));
            *(uint4*)((unsigned char*)Cb + (brow + row) * 512 + cbyte) = d;
        }
    } else {
#pragma unroll
        for (int n = 0; n < 8; ++n) {
            const int c0 = ch * 128 + n * 16 + kg * 4;
            const f32x4 bv = *(const f32x4*)(b2 + c0);
            f32x4 v = acc2[n] + bv;
            *(f32x4*)(smem + ((arow * 1024 + c0 * 4) ^ swz)) = v;
        }
        __syncthreads();
#pragma unroll
        for (int q = 0; q < 8; ++q) {
            const int flat = q * 4096 + tid * 16;
            const int row = flat >> 10, cbyte = flat & 1023;
            f32x4 v = *(const f32x4*)(smem + ((row * 1024 + cbyte) ^ ((row & 7) << 4)));
            const long base = (brow + row) * 256 + (cbyte >> 2);
            f32x4 xo = *(const f32x4*)(Xf + base);
            f32x4 nx = xo + v;
            *(f32x4*)(Xf + base) = nx;
            uint2 p;
            p.x = (unsigned)f2b(nx[0]) | ((unsigned)f2b(nx[1]) << 16);
            p.y = (unsigned)f2b(nx[2]) | ((unsigned)f2b(nx[3]) << 16);
            *(uint2*)(Xb + base) = p;
        }
    }
}

// ---------------- small kernels ----------------
__global__ void k_offsets(const int* __restrict__ num_nodes, int* __restrict__ off) {
    __shared__ int s[Bb];
    int t = threadIdx.x;
    s[t] = num_nodes[t];
    __syncthreads();
    for (int d = 1; d < Bb; d <<= 1) {
        int v = (t >= d) ? s[t - d] : 0;
        __syncthreads();
        s[t] += v;
        __syncthreads();
    }
    off[t + 1] = s[t];
    if (t == 0) off[0] = 0;
}

__global__ void k_edgeprep(const int* __restrict__ edges, const int* __restrict__ off,
                           int* __restrict__ gsrc, int* __restrict__ gdst, int* __restrict__ cnt) {
    int ge = blockIdx.x * 256 + threadIdx.x;
    if (ge >= TE) return;
    int b = ge >> 11;
    int o = off[b];
    gsrc[ge] = edges[ge * 2 + 0] + o;
    int d = edges[ge * 2 + 1] + o;
    gdst[ge] = d;
    atomicAdd(&cnt[d], 1);
}

__global__ void k_scan(const int* __restrict__ cnt, int* __restrict__ coff, int* __restrict__ pos) {
    __shared__ int part[1024];
    int t = threadIdx.x;
    int loc[8];
    int s = 0;
#pragma unroll
    for (int j = 0; j < 8; ++j) { loc[j] = cnt[t * 8 + j]; s += loc[j]; }
    part[t] = s;
    __syncthreads();
    for (int d = 1; d < 1024; d <<= 1) {
        int v = (t >= d) ? part[t - d] : 0;
        __syncthreads();
        part[t] += v;
        __syncthreads();
    }
    int base = part[t] - s;
#pragma unroll
    for (int j = 0; j < 8; ++j) {
        int idx = t * 8 + j;
        coff[idx] = base;
        pos[idx]  = base;
        base += loc[j];
    }
    if (t == 1023) coff[TN] = part[1023];
}

__global__ void k_fill(const int* __restrict__ gdst, const int* __restrict__ gsrc,
                       const float* __restrict__ ef,
                       int* __restrict__ pos, int* __restrict__ gsrcs,
                       float* __restrict__ dcsr) {
    int ge = blockIdx.x * 256 + threadIdx.x;
    if (ge >= TE) return;
    int d = gdst[ge];
    int p = atomicAdd(&pos[d], 1);
    gsrcs[p] = gsrc[ge];
    dcsr[p]  = ef[ge];
}

__global__ void k_rbfgrid(unsigned short* __restrict__ rbfg) {
    int gid = blockIdx.x * 256 + threadIdx.x;   // TABN * 64
    int i = gid >> 6, k = gid & 63;
    float v = 0.f;
    if (k < EDGE) {
        float d = (float)i / TSCALE;
        float t = d - 0.1f * (float)k;
        v = __expf(-50.f * t * t);
    }
    rbfg[gid] = f2b(v);
}

__global__ void k_embed(const int* __restrict__ nodes, const float* __restrict__ embed,
                        float* __restrict__ x, unsigned short* __restrict__ xb) {
    int gid = blockIdx.x * 256 + threadIdx.x;
    int i = gid >> 8, c = gid & 255;
    float v = embed[(nodes[i] << 8) + c];
    x[gid] = v;
    xb[gid] = f2b(v);
}

__global__ void k_wprep(const float* __restrict__ me_w1, const float* __restrict__ me_w2,
                        const float* __restrict__ mn_w1, const float* __restrict__ mn_w2,
                        const float* __restrict__ st_w1, const float* __restrict__ st_w2,
                        const float* __restrict__ ro_w1,
                        unsigned short* __restrict__ me1T, unsigned short* __restrict__ me2T,
                        unsigned short* __restrict__ mn1T, unsigned short* __restrict__ mn2T,
                        unsigned short* __restrict__ st1T, unsigned short* __restrict__ st2T,
                        unsigned short* __restrict__ ro1T) {
    int gid = blockIdx.x * 256 + threadIdx.x;
    const int S1 = Ll * 256 * EKPAD;
    if (gid < S1) {
        int i = gid / (256 * EKPAD);
        int r = gid % (256 * EKPAD);
        int n = r / EKPAD, k = r % EKPAD;
        float v = (k < EDGE) ? me_w1[(i * EDGE + k) * 256 + n] : 0.f;
        me1T[gid] = f2b(v);
        return;
    }
    gid -= S1;
    const int S2 = Ll * 256 * 256;
    const float* srcs[5] = { me_w2, mn_w1, mn_w2, st_w1, st_w2 };
    unsigned short* dsts[5] = { me2T, mn1T, mn2T, st1T, st2T };
#pragma unroll
    for (int q = 0; q < 5; ++q) {
        if (gid < S2) {
            int i = gid >> 16;
            int r = gid & 65535;
            int n = r >> 8, k = r & 255;
            dsts[q][gid] = f2b(srcs[q][(i << 16) + k * 256 + n]);
            return;
        }
        gid -= S2;
    }
    int n = gid >> 8, k = gid & 255;
    ro1T[gid] = f2b(ro_w1[k * 256 + n]);
}

// edge aggregation via gate-table lerp (R11-verified)
__global__ void k_aggtab(const float* __restrict__ dcsr,
                         const unsigned short* __restrict__ tab,
                         const unsigned short* __restrict__ nmsgb,
                         const int* __restrict__ coff,
                         const int* __restrict__ gsrcs,
                         unsigned short* __restrict__ msum) {
    int tid = threadIdx.x;
    int which = tid >> 5, local = tid & 31;
    int n = blockIdx.x * 8 + which;
    int c0 = local * 8;
    float s0 = 0.f, s1 = 0.f, s2 = 0.f, s3 = 0.f, s4 = 0.f, s5 = 0.f, s6 = 0.f, s7 = 0.f;
    int beg = coff[n], end = coff[n + 1];
    for (int i = beg; i < end; ++i) {
        float d  = dcsr[i];
        int   sr = gsrcs[i];
        float xx = d * TSCALE;
        int   i0 = (int)xx;
        float f  = xx - (float)i0;
        ushort8 g0 = *(const ushort8*)(tab + (long)i0 * 256 + c0);
        ushort8 g1 = *(const ushort8*)(tab + (long)(i0 + 1) * 256 + c0);
        ushort8 nm = *(const ushort8*)(nmsgb + ((long)sr << 8) + c0);
        float a0 = b2f(g0[0]), a1 = b2f(g0[1]), a2 = b2f(g0[2]), a3 = b2f(g0[3]);
        float a4 = b2f(g0[4]), a5 = b2f(g0[5]), a6 = b2f(g0[6]), a7 = b2f(g0[7]);
        s0 += (a0 + (b2f(g1[0]) - a0) * f) * b2f(nm[0]);
        s1 += (a1 + (b2f(g1[1]) - a1) * f) * b2f(nm[1]);
        s2 += (a2 + (b2f(g1[2]) - a2) * f) * b2f(nm[2]);
        s3 += (a3 + (b2f(g1[3]) - a3) * f) * b2f(nm[3]);
        s4 += (a4 + (b2f(g1[4]) - a4) * f) * b2f(nm[4]);
        s5 += (a5 + (b2f(g1[5]) - a5) * f) * b2f(nm[5]);
        s6 += (a6 + (b2f(g1[6]) - a6) * f) * b2f(nm[6]);
        s7 += (a7 + (b2f(g1[7]) - a7) * f) * b2f(nm[7]);
    }
    ushort8 o;
    o[0] = f2b(s0); o[1] = f2b(s1); o[2] = f2b(s2); o[3] = f2b(s3);
    o[4] = f2b(s4); o[5] = f2b(s5); o[6] = f2b(s6); o[7] = f2b(s7);
    *(ushort8*)(msum + ((long)n << 8) + c0) = o;
}

__global__ void k_readout(const unsigned short* __restrict__ t, const float* __restrict__ w2,
                          const float* __restrict__ b2, const int* __restrict__ num_nodes,
                          const float* __restrict__ evw, const float* __restrict__ evb,
                          float* __restrict__ out) {
    __shared__ float red[256];
    int b = blockIdx.x, tid = threadIdx.x;
    const unsigned short* tb = t + (long)b * Nn * 256;
    float part = 0.f;
    for (int i = tid; i < Nn * 256; i += 256)
        part += b2f(tb[i]) * w2[i & 255];
    red[tid] = part;
    __syncthreads();
    for (int d = 128; d > 0; d >>= 1) {
        if (tid < d) red[tid] += red[tid + d];
        __syncthreads();
    }
    if (tid == 0) {
        float g = red[0] + (float)Nn * b2[0];
        g = g * 2.0f + (-1.5f) * (float)num_nodes[b];
        out[b * 4 + 0] = g * evw[0] + evb[0];
        out[b * 4 + 1] = spf(g * evw[1] + evb[1]);
        out[b * 4 + 2] = spf(g * evw[2] + evb[2]) + 1.f;
        out[b * 4 + 3] = spf(g * evw[3] + evb[3]);
    }
}

// ---------------- workspace layout ----------------
constexpr size_t al(size_t x) { return (x + 255) & ~(size_t)255; }
constexpr size_t O_OFF    = 0;
constexpr size_t O_GSRC   = al(O_OFF + 65 * 4);
constexpr size_t O_GDST   = al(O_GSRC + (size_t)TE * 4);
constexpr size_t O_CNT    = al(O_GDST + (size_t)TE * 4);
constexpr size_t O_COFF   = al(O_CNT + (size_t)TN * 4);
constexpr size_t O_POS    = al(O_COFF + (size_t)(TN + 1) * 4);
constexpr size_t O_GSRCS  = al(O_POS + (size_t)TN * 4);
constexpr size_t O_DCSR   = al(O_GSRCS + (size_t)TE * 4);
constexpr size_t O_RBFG   = al(O_DCSR + (size_t)TE * 4);
constexpr size_t O_TTAB   = al(O_RBFG + (size_t)TABN * EKPAD * 2);
constexpr size_t O_GTAB   = al(O_TTAB + (size_t)Ll * TABN * 256 * 2);
constexpr size_t O_ME1T   = al(O_GTAB + (size_t)Ll * TABN * 256 * 2);
constexpr size_t O_ME2T   = al(O_ME1T + (size_t)Ll * 256 * EKPAD * 2);
constexpr size_t O_MN1T   = al(O_ME2T + (size_t)Ll * 256 * 256 * 2);
constexpr size_t O_MN2T   = al(O_MN1T + (size_t)Ll * 256 * 256 * 2);
constexpr size_t O_ST1T   = al(O_MN2T + (size_t)Ll * 256 * 256 * 2);
constexpr size_t O_ST2T   = al(O_ST1T + (size_t)Ll * 256 * 256 * 2);
constexpr size_t O_RO1T   = al(O_ST2T + (size_t)Ll * 256 * 256 * 2);
constexpr size_t O_X      = al(O_RO1T + (size_t)256 * 256 * 2);
constexpr size_t O_XB     = al(O_X + (size_t)TN * 256 * 4);
constexpr size_t O_TMPB   = al(O_XB + (size_t)TN * 256 * 2);
constexpr size_t O_NMSG   = al(O_TMPB + (size_t)TN * 256 * 2);
constexpr size_t O_MSUM   = al(O_NMSG + (size_t)TN * 256 * 2);
constexpr size_t WS_NEED  = al(O_MSUM + (size_t)TN * 256 * 2);

extern "C" void kernel_launch(void* const* d_in, const int* in_sizes, int n_in,
                              void* d_out, int out_size, void* d_ws, size_t ws_size,
                              hipStream_t stream) {
    if (ws_size < WS_NEED) return;

    const int*   nodes     = (const int*)d_in[0];
    const int*   num_nodes = (const int*)d_in[1];
    const int*   edges     = (const int*)d_in[2];
    const float* efeat     = (const float*)d_in[3];
    const float* embed     = (const float*)d_in[5];
    const float* me_w1 = (const float*)d_in[6],  *me_b1 = (const float*)d_in[7];
    const float* me_w2 = (const float*)d_in[8],  *me_b2 = (const float*)d_in[9];
    const float* mn_w1 = (const float*)d_in[10], *mn_b1 = (const float*)d_in[11];
    const float* mn_w2 = (const float*)d_in[12], *mn_b2 = (const float*)d_in[13];
    const float* st_w1 = (const float*)d_in[14], *st_b1 = (const float*)d_in[15];
    const float* st_w2 = (const float*)d_in[16], *st_b2 = (const float*)d_in[17];
    const float* ro_w1 = (const float*)d_in[18], *ro_b1 = (const float*)d_in[19];
    const float* ro_w2 = (const float*)d_in[20], *ro_b2 = (const float*)d_in[21];
    const float* ev_w  = (const float*)d_in[22], *ev_b  = (const float*)d_in[23];

    char* ws = (char*)d_ws;
    int* off   = (int*)(ws + O_OFF);
    int* gsrc  = (int*)(ws + O_GSRC);
    int* gdst  = (int*)(ws + O_GDST);
    int* cnt   = (int*)(ws + O_CNT);
    int* coff  = (int*)(ws + O_COFF);
    int* pos   = (int*)(ws + O_POS);
    int* gsrcs = (int*)(ws + O_GSRCS);
    float* dcsr = (float*)(ws + O_DCSR);
    unsigned short* rbfg  = (unsigned short*)(ws + O_RBFG);
    unsigned short* ttab  = (unsigned short*)(ws + O_TTAB);
    unsigned short* gtab  = (unsigned short*)(ws + O_GTAB);
    unsigned short* me1T  = (unsigned short*)(ws + O_ME1T);
    unsigned short* me2T  = (unsigned short*)(ws + O_ME2T);
    unsigned short* mn1T  = (unsigned short*)(ws + O_MN1T);
    unsigned short* mn2T  = (unsigned short*)(ws + O_MN2T);
    unsigned short* st1T  = (unsigned short*)(ws + O_ST1T);
    unsigned short* st2T  = (unsigned short*)(ws + O_ST2T);
    unsigned short* ro1T  = (unsigned short*)(ws + O_RO1T);
    float*          x     = (float*)(ws + O_X);
    unsigned short* xb    = (unsigned short*)(ws + O_XB);
    unsigned short* tmpb  = (unsigned short*)(ws + O_TMPB);
    unsigned short* nmsgb = (unsigned short*)(ws + O_NMSG);
    unsigned short* msum  = (unsigned short*)(ws + O_MSUM);
    float* out = (float*)d_out;

    hipMemsetAsync(cnt, 0, TN * 4, stream);
    k_offsets<<<1, Bb, 0, stream>>>(num_nodes, off);
    k_edgeprep<<<TE / 256, 256, 0, stream>>>(edges, off, gsrc, gdst, cnt);
    k_scan<<<1, 1024, 0, stream>>>(cnt, coff, pos);
    k_fill<<<TE / 256, 256, 0, stream>>>(gdst, gsrc, efeat, pos, gsrcs, dcsr);
    k_rbfgrid<<<(TABN * EKPAD) / 256, 256, 0, stream>>>(rbfg);
    k_embed<<<TN, 256, 0, stream>>>(nodes, embed, x, xb);
    {
        const int total = Ll * 256 * EKPAD + 5 * Ll * 256 * 256 + 256 * 256;
        k_wprep<<<total / 256, 256, 0, stream>>>(me_w1, me_w2, mn_w1, mn_w2, st_w1, st_w2, ro_w1,
                                                 me1T, me2T, mn1T, mn2T, st1T, st2T, ro1T);
    }

    // ---- build all 6 layers' gate tables in 2 batched dispatches (z = layer) ----
    const dim3 gT(2, TABN / 128, Ll), gN(2, TN / 64, 1), blk(256);
    gemm_k<1, 0, 128><<<gT, blk, 0, stream>>>(rbfg, me1T, me_b1, ttab, nullptr, nullptr,
                                              TABN, EKPAD,
                                              0, 256 * EKPAD, 256, (long)TABN * 256);
    gemm_k<0, 0, 128><<<gT, blk, 0, stream>>>(ttab, me2T, me_b2, gtab, nullptr, nullptr,
                                              TABN, 256,
                                              (long)TABN * 256, 65536, 256, (long)TABN * 256);

    for (int i = 0; i < Ll; ++i) {
        fused_node<0><<<TN / 32, 256, 0, stream>>>(
            xb, mn1T + i * 65536, mn_b1 + i * 256,
            mn2T + i * 65536, mn_b2 + i * 256, nmsgb, nullptr, nullptr);
        k_aggtab<<<TN / 8, 256, 0, stream>>>(dcsr, gtab + (size_t)i * TABN * 256,
                                             nmsgb, coff, gsrcs, msum);
        fused_node<2><<<TN / 32, 256, 0, stream>>>(
            msum, st1T + i * 65536, st_b1 + i * 256,
            st2T + i * 65536, st_b2 + i * 256, nullptr, x, xb);
    }

    gemm_k<1, 0, 64><<<gN, blk, 0, stream>>>(xb, ro1T, ro_b1, tmpb, nullptr, nullptr,
                                             TN, 256, 0, 0, 0, 0);
    k_readout<<<Bb, 256, 0, stream>>>(tmpb, ro_w2, ro_b2, num_nodes, ev_w, ev_b, out);
}

// Round 13
// 476.799 us; speedup vs baseline: 2.9409x; 1.0770x over previous
//
#include <hip/hip_runtime.h>

#define Bb 64
#define Nn 128
#define Ee 2048
#define Hh 256
#define Ll 6
#define TN 8192
#define TE 131072
#define EDGE 50
#define EKPAD 64
#define TABN 4096
#define TSCALE ((float)(TABN - 2) / 5.0f)

typedef __attribute__((ext_vector_type(4))) float f32x4;
typedef __attribute__((ext_vector_type(8))) __bf16 bf16x8;
typedef __attribute__((ext_vector_type(8))) unsigned short ushort8;

__device__ inline float b2f(unsigned short u) {
    union { unsigned u; float f; } v; v.u = ((unsigned)u) << 16; return v.f;
}
__device__ inline unsigned short f2b(float f) {
    union { float f; unsigned u; } v; v.f = f;
    unsigned r = v.u + 0x7fffu + ((v.u >> 16) & 1u);
    return (unsigned short)(r >> 16);
}
__device__ inline float spf(float x) {
    return fmaxf(x, 0.f) + __logf(1.f + __expf(-fabsf(x)));
}
__device__ inline float sspf(float x) {
    return spf(x) - 0.69314718055994530942f;
}

// ---------------- GEMM (R4-verified) + z-batch strides ----------------
template <int ACT, int OUTMODE, int TM>
__global__ __launch_bounds__(256)
void gemm_k(const unsigned short* __restrict__ A,
            const unsigned short* __restrict__ WT,
            const float* __restrict__ bias,
            unsigned short* __restrict__ Cb,
            float* __restrict__ Xf,
            unsigned short* __restrict__ Xb,
            int M, int K,
            long Az, long Wz, long bz, long Cz)
{
    constexpr int BK  = 64;
    constexpr int TNc = 128;
    constexpr int MR  = TM / 32;
    constexpr int NR  = 4;
    constexpr int STAGE_B = (TM + TNc) * BK * 2;
    constexpr int EPI_B   = (OUTMODE == 2) ? TM * TNc * 4 : TM * TNc * 2;
    constexpr int SMEM_B  = STAGE_B > EPI_B ? STAGE_B : EPI_B;

    __shared__ __align__(16) unsigned char smem[SMEM_B];
    unsigned short* As = (unsigned short*)smem;
    unsigned short* Bs = As + TM * BK;

    const int z = blockIdx.z;
    A += z * Az; WT += z * Wz; bias += z * bz;
    if (Cb) Cb += z * Cz;

    const int tid  = threadIdx.x;
    const int lane = tid & 63;
    const int w    = tid >> 6;
    const int wr   = w >> 1, wc = w & 1;
    const int r16  = lane & 15;
    const int kg   = lane >> 4;

    const long brow = (long)blockIdx.y * TM;
    const int  bcol = blockIdx.x * TNc;

    constexpr int ACH = TM / 8;
    constexpr int NCH = ACH + TNc / 8;
    constexpr int IPW = NCH / 4;
    const int lrow  = lane >> 3;
    const int lslot = lane & 7;

    f32x4 acc[MR][NR];
#pragma unroll
    for (int m = 0; m < MR; ++m)
#pragma unroll
        for (int n = 0; n < NR; ++n) acc[m][n] = f32x4{0.f, 0.f, 0.f, 0.f};

    for (int k0 = 0; k0 < K; k0 += BK) {
        __syncthreads();
#pragma unroll
        for (int i = 0; i < IPW; ++i) {
            const int c    = w * IPW + i;
            const bool isA = c < ACH;
            const int cc   = isA ? c : c - ACH;
            const int srow = cc * 8 + lrow;
            const int kch  = lslot ^ (srow & 7);
            const unsigned short* gp = isA
                ? A  + (brow + srow) * (long)K + k0 + kch * 8
                : WT + (bcol + srow) * (long)K + k0 + kch * 8;
            unsigned short* lp = (isA ? As : Bs) + cc * 512;
            __builtin_amdgcn_global_load_lds(
                (const __attribute__((address_space(1))) void*)gp,
                (__attribute__((address_space(3))) void*)lp, 16, 0, 0);
        }
        __syncthreads();

        bf16x8 a[MR][2], b[NR][2];
#pragma unroll
        for (int m = 0; m < MR; ++m) {
            const int row = wr * (MR * 16) + m * 16 + r16;
            const unsigned short* base = As + row * BK;
#pragma unroll
            for (int kk = 0; kk < 2; ++kk) {
                const int slot = (kk * 4 + kg) ^ (row & 7);
                a[m][kk] = *(const bf16x8*)(base + slot * 8);
            }
        }
#pragma unroll
        for (int n = 0; n < NR; ++n) {
            const int row = wc * 64 + n * 16 + r16;
            const unsigned short* base = Bs + row * BK;
#pragma unroll
            for (int kk = 0; kk < 2; ++kk) {
                const int slot = (kk * 4 + kg) ^ (row & 7);
                b[n][kk] = *(const bf16x8*)(base + slot * 8);
            }
        }
#pragma unroll
        for (int kk = 0; kk < 2; ++kk)
#pragma unroll
            for (int m = 0; m < MR; ++m)
#pragma unroll
                for (int n = 0; n < NR; ++n)
                    acc[m][n] = __builtin_amdgcn_mfma_f32_16x16x32_bf16(
                        b[n][kk], a[m][kk], acc[m][n], 0, 0, 0);
    }

    __syncthreads();

    if (OUTMODE != 2) {
#pragma unroll
        for (int m = 0; m < MR; ++m) {
            const int row = wr * (MR * 16) + m * 16 + r16;
#pragma unroll
            for (int n = 0; n < NR; ++n) {
                const int colL = wc * 64 + n * 16 + kg * 4;
                const f32x4 bv = *(const f32x4*)(bias + bcol + colL);
                float v0 = acc[m][n][0] + bv[0];
                float v1 = acc[m][n][1] + bv[1];
                float v2 = acc[m][n][2] + bv[2];
                float v3 = acc[m][n][3] + bv[3];
                if (ACT) { v0 = sspf(v0); v1 = sspf(v1); v2 = sspf(v2); v3 = sspf(v3); }
                uint2 p;
                p.x = (unsigned)f2b(v0) | ((unsigned)f2b(v1) << 16);
                p.y = (unsigned)f2b(v2) | ((unsigned)f2b(v3) << 16);
                const int off = (row * 256 + colL * 2) ^ ((row & 7) << 4);
                *(uint2*)(smem + off) = p;
            }
        }
        __syncthreads();
        constexpr int ITER = TM / 16;
#pragma unroll
        for (int q = 0; q < ITER; ++q) {
            const int flat = q * 4096 + tid * 16;
            const int row = flat >> 8, cbyte = flat & 255;
            uint4 d = *(const uint4*)(smem + ((row * 256 + cbyte) ^ ((row & 7) << 4)));
            *(uint4*)((unsigned char*)Cb + (brow + row) * 512 + bcol * 2 + cbyte) = d;
        }
    } else {
#pragma unroll
        for (int m = 0; m < MR; ++m) {
            const int row = wr * (MR * 16) + m * 16 + r16;
#pragma unroll
            for (int n = 0; n < NR; ++n) {
                const int colL = wc * 64 + n * 16 + kg * 4;
                const f32x4 bv = *(const f32x4*)(bias + bcol + colL);
                f32x4 v = acc[m][n] + bv;
                const int off = (row * 512 + colL * 4) ^ ((row & 7) << 4);
                *(f32x4*)(smem + off) = v;
            }
        }
        __syncthreads();
        constexpr int ITER = TM / 8;
#pragma unroll
        for (int q = 0; q < ITER; ++q) {
            const int flat = q * 4096 + tid * 16;
            const int row = flat >> 9, cbyte = flat & 511;
            f32x4 v = *(const f32x4*)(smem + ((row * 512 + cbyte) ^ ((row & 7) << 4)));
            const long base = (brow + row) * 256 + bcol + (cbyte >> 2);
            f32x4 xo = *(const f32x4*)(Xf + base);
            f32x4 nx = xo + v;
            *(f32x4*)(Xf + base) = nx;
            uint2 p;
            p.x = (unsigned)f2b(nx[0]) | ((unsigned)f2b(nx[1]) << 16);
            p.y = (unsigned)f2b(nx[2]) | ((unsigned)f2b(nx[3]) << 16);
            *(uint2*)(Xb + base) = p;
        }
    }
}

// ======== fused node MLP, 16-row tiles: 512 blocks, 2 blocks/CU ========
// out = [ssp(A @ W1T^T + b1)] @ W2T^T + b2 ; 4 waves, wave w owns cols [w*64,w*64+64).
// Lane mapping (R4/R12-verified swapped MFMA): row = r16, col = .. + kg*4 + j.
// AGG=0: A staged from bf16 global via global_load_lds.
// AGG=1: A = segment-aggregation  sum_e lerp(tab,d_e)*nmsg[src_e]  built in-register
//        (16 thr/node x 16 ch, R11-verified lerp math) -> swizzled A_lds.
// OUTMODE 0: Cb = bf16 result. 2: Xf += v; Xb = f2b(Xf).
template <int OUTMODE, int AGG>
__global__ __launch_bounds__(256, 2)
void fused_node16(const unsigned short* __restrict__ Ab,
                  const unsigned short* __restrict__ W1T,
                  const float* __restrict__ b1,
                  const unsigned short* __restrict__ W2T,
                  const float* __restrict__ b2,
                  unsigned short* __restrict__ Cb,
                  float* __restrict__ Xf,
                  unsigned short* __restrict__ Xb,
                  const float* __restrict__ dcsr,
                  const unsigned short* __restrict__ tab,
                  const unsigned short* __restrict__ nmsgb,
                  const int* __restrict__ coff,
                  const int* __restrict__ gsrcs)
{
    __shared__ __align__(16) unsigned char smem[16384];       // A(8K) + t(8K)
    unsigned short* A_lds = (unsigned short*)smem;            // 16 x 256 bf16
    unsigned char*  t_lds = smem + 8192;                      // 16 x 256 bf16

    const int tid  = threadIdx.x;
    const int lane = tid & 63;
    const int w    = tid >> 6;            // 4 waves; wave w: cols [w*64, w*64+64)
    const int r16  = lane & 15;
    const int kg   = lane >> 4;
    const long brow = (long)blockIdx.x * 16;

    if (!AGG) {
        // stage A: 8 chunks x 1KB (2 rows each), 2 per wave
        const int lrow  = lane >> 5;
        const int lslot = lane & 31;
#pragma unroll
        for (int i = 0; i < 2; ++i) {
            const int cc   = w * 2 + i;
            const int srow = cc * 2 + lrow;
            const int kch  = lslot ^ (srow & 7);
            const unsigned short* gp = Ab + (brow + srow) * 256 + kch * 8;
            __builtin_amdgcn_global_load_lds(
                (const __attribute__((address_space(1))) void*)gp,
                (__attribute__((address_space(3))) void*)(A_lds + cc * 512), 16, 0, 0);
        }
    } else {
        // in-kernel aggregation: node = tid>>4 (0..15), 16 channels per thread
        const int node = tid >> 4;
        const int c0   = (tid & 15) * 16;
        const int gn   = (int)brow + node;
        float s[16];
#pragma unroll
        for (int j = 0; j < 16; ++j) s[j] = 0.f;
        const int beg = coff[gn], end = coff[gn + 1];
        for (int i = beg; i < end; ++i) {
            const float d  = dcsr[i];
            const int   sr = gsrcs[i];
            const float xx = d * TSCALE;
            const int   i0 = (int)xx;
            const float f  = xx - (float)i0;
            const unsigned short* t0 = tab + (long)i0 * 256 + c0;
            ushort8 g0a = *(const ushort8*)t0;
            ushort8 g0b = *(const ushort8*)(t0 + 8);
            ushort8 g1a = *(const ushort8*)(t0 + 256);
            ushort8 g1b = *(const ushort8*)(t0 + 264);
            const unsigned short* np = nmsgb + ((long)sr << 8) + c0;
            ushort8 na = *(const ushort8*)np;
            ushort8 nb = *(const ushort8*)(np + 8);
#pragma unroll
            for (int j = 0; j < 8; ++j) {
                float a = b2f(g0a[j]);
                s[j] += (a + (b2f(g1a[j]) - a) * f) * b2f(na[j]);
            }
#pragma unroll
            for (int j = 0; j < 8; ++j) {
                float a = b2f(g0b[j]);
                s[8 + j] += (a + (b2f(g1b[j]) - a) * f) * b2f(nb[j]);
            }
        }
        const int swzn = (node & 7) << 4;
#pragma unroll
        for (int j = 0; j < 4; ++j) {
            uint2 p;
            p.x = (unsigned)f2b(s[j * 4 + 0]) | ((unsigned)f2b(s[j * 4 + 1]) << 16);
            p.y = (unsigned)f2b(s[j * 4 + 2]) | ((unsigned)f2b(s[j * 4 + 3]) << 16);
            const int c = c0 + j * 4;
            *(uint2*)((unsigned char*)A_lds + ((node * 512 + c * 2) ^ swzn)) = p;
        }
    }
    __syncthreads();

    const int arow = r16;                 // 16 rows, lane r16 <-> row
    const int swz  = (arow & 7) << 4;

    // ---- GEMM1: t[arow][w*64 + n*16 + kg*4 + j] ----
    f32x4 acc1[4];
#pragma unroll
    for (int n = 0; n < 4; ++n) acc1[n] = f32x4{0.f, 0.f, 0.f, 0.f};
#pragma unroll
    for (int kk = 0; kk < 8; ++kk) {
        const int slot = (kk * 4 + kg) ^ (arow & 7);
        bf16x8 af = *(const bf16x8*)(A_lds + arow * 256 + slot * 8);
#pragma unroll
        for (int n = 0; n < 4; ++n) {
            const int col = w * 64 + n * 16 + r16;
            bf16x8 wf = *(const bf16x8*)(W1T + col * 256 + kk * 32 + kg * 8);
            acc1[n] = __builtin_amdgcn_mfma_f32_16x16x32_bf16(wf, af, acc1[n], 0, 0, 0);
        }
    }
#pragma unroll
    for (int n = 0; n < 4; ++n) {
        const int c0 = w * 64 + n * 16 + kg * 4;
        const f32x4 bv = *(const f32x4*)(b1 + c0);
        uint2 p;
        p.x = (unsigned)f2b(sspf(acc1[n][0] + bv[0])) |
              ((unsigned)f2b(sspf(acc1[n][1] + bv[1])) << 16);
        p.y = (unsigned)f2b(sspf(acc1[n][2] + bv[2])) |
              ((unsigned)f2b(sspf(acc1[n][3] + bv[3])) << 16);
        *(uint2*)(t_lds + ((arow * 512 + c0 * 2) ^ swz)) = p;
    }
    __syncthreads();

    // ---- GEMM2 ----
    f32x4 acc2[4];
#pragma unroll
    for (int n = 0; n < 4; ++n) acc2[n] = f32x4{0.f, 0.f, 0.f, 0.f};
#pragma unroll
    for (int kk = 0; kk < 8; ++kk) {
        bf16x8 af = *(const bf16x8*)(t_lds + ((arow * 512 + kk * 64 + kg * 16) ^ swz));
#pragma unroll
        for (int n = 0; n < 4; ++n) {
            const int col = w * 64 + n * 16 + r16;
            bf16x8 wf = *(const bf16x8*)(W2T + col * 256 + kk * 32 + kg * 8);
            acc2[n] = __builtin_amdgcn_mfma_f32_16x16x32_bf16(wf, af, acc2[n], 0, 0, 0);
        }
    }
    __syncthreads();   // A,t dead -> epilogue tile (full 16KB)

    if (OUTMODE == 0) {
#pragma unroll
        for (int n = 0; n < 4; ++n) {
            const int c0 = w * 64 + n * 16 + kg * 4;
            const f32x4 bv = *(const f32x4*)(b2 + c0);
            uint2 p;
            p.x = (unsigned)f2b(acc2[n][0] + bv[0]) | ((unsigned)f2b(acc2[n][1] + bv[1]) << 16);
            p.y = (unsigned)f2b(acc2[n][2] + bv[2]) | ((unsigned)f2b(acc2[n][3] + bv[3]) << 16);
            *(uint2*)(smem + ((arow * 512 + c0 * 2) ^ swz)) = p;
        }
        __syncthreads();
#pragma unroll
        for (int q = 0; q < 2; ++q) {
            const int flat = q * 4096 + tid * 16;
            const int row = flat >> 9, cbyte = flat & 511;
            uint4 d = *(const uint4*)(smem + ((row * 512 + cbyte) ^ ((row & 7) << 4)));
            *(uint4*)((unsigned char*)Cb + (brow + row) * 512 + cbyte) = d;
        }
    } else {
#pragma unroll
        for (int n = 0; n < 4; ++n) {
            const int c0 = w * 64 + n * 16 + kg * 4;
            const f32x4 bv = *(const f32x4*)(b2 + c0);
            f32x4 v = acc2[n] + bv;
            *(f32x4*)(smem + ((arow * 1024 + c0 * 4) ^ swz)) = v;
        }
        __syncthreads();
#pragma unroll
        for (int q = 0; q < 4; ++q) {
            const int flat = q * 4096 + tid * 16;
            const int row = flat >> 10, cbyte = flat & 1023;
            f32x4 v = *(const f32x4*)(smem + ((row * 1024 + cbyte) ^ ((row & 7) << 4)));
            const long base = (brow + row) * 256 + (cbyte >> 2);
            f32x4 xo = *(const f32x4*)(Xf + base);
            f32x4 nx = xo + v;
            *(f32x4*)(Xf + base) = nx;
            uint2 p;
            p.x = (unsigned)f2b(nx[0]) | ((unsigned)f2b(nx[1]) << 16);
            p.y = (unsigned)f2b(nx[2]) | ((unsigned)f2b(nx[3]) << 16);
            *(uint2*)(Xb + base) = p;
        }
    }
}

// ---------------- small kernels ----------------
__global__ void k_offsets(const int* __restrict__ num_nodes, int* __restrict__ off) {
    __shared__ int s[Bb];
    int t = threadIdx.x;
    s[t] = num_nodes[t];
    __syncthreads();
    for (int d = 1; d < Bb; d <<= 1) {
        int v = (t >= d) ? s[t - d] : 0;
        __syncthreads();
        s[t] += v;
        __syncthreads();
    }
    off[t + 1] = s[t];
    if (t == 0) off[0] = 0;
}

__global__ void k_edgeprep(const int* __restrict__ edges, const int* __restrict__ off,
                           int* __restrict__ gsrc, int* __restrict__ gdst, int* __restrict__ cnt) {
    int ge = blockIdx.x * 256 + threadIdx.x;
    if (ge >= TE) return;
    int b = ge >> 11;
    int o = off[b];
    gsrc[ge] = edges[ge * 2 + 0] + o;
    int d = edges[ge * 2 + 1] + o;
    gdst[ge] = d;
    atomicAdd(&cnt[d], 1);
}

__global__ void k_scan(const int* __restrict__ cnt, int* __restrict__ coff, int* __restrict__ pos) {
    __shared__ int part[1024];
    int t = threadIdx.x;
    int loc[8];
    int s = 0;
#pragma unroll
    for (int j = 0; j < 8; ++j) { loc[j] = cnt[t * 8 + j]; s += loc[j]; }
    part[t] = s;
    __syncthreads();
    for (int d = 1; d < 1024; d <<= 1) {
        int v = (t >= d) ? part[t - d] : 0;
        __syncthreads();
        part[t] += v;
        __syncthreads();
    }
    int base = part[t] - s;
#pragma unroll
    for (int j = 0; j < 8; ++j) {
        int idx = t * 8 + j;
        coff[idx] = base;
        pos[idx]  = base;
        base += loc[j];
    }
    if (t == 1023) coff[TN] = part[1023];
}

__global__ void k_fill(const int* __restrict__ gdst, const int* __restrict__ gsrc,
                       const float* __restrict__ ef,
                       int* __restrict__ pos, int* __restrict__ gsrcs,
                       float* __restrict__ dcsr) {
    int ge = blockIdx.x * 256 + threadIdx.x;
    if (ge >= TE) return;
    int d = gdst[ge];
    int p = atomicAdd(&pos[d], 1);
    gsrcs[p] = gsrc[ge];
    dcsr[p]  = ef[ge];
}

__global__ void k_rbfgrid(unsigned short* __restrict__ rbfg) {
    int gid = blockIdx.x * 256 + threadIdx.x;   // TABN * 64
    int i = gid >> 6, k = gid & 63;
    float v = 0.f;
    if (k < EDGE) {
        float d = (float)i / TSCALE;
        float t = d - 0.1f * (float)k;
        v = __expf(-50.f * t * t);
    }
    rbfg[gid] = f2b(v);
}

__global__ void k_embed(const int* __restrict__ nodes, const float* __restrict__ embed,
                        float* __restrict__ x, unsigned short* __restrict__ xb) {
    int gid = blockIdx.x * 256 + threadIdx.x;
    int i = gid >> 8, c = gid & 255;
    float v = embed[(nodes[i] << 8) + c];
    x[gid] = v;
    xb[gid] = f2b(v);
}

__global__ void k_wprep(const float* __restrict__ me_w1, const float* __restrict__ me_w2,
                        const float* __restrict__ mn_w1, const float* __restrict__ mn_w2,
                        const float* __restrict__ st_w1, const float* __restrict__ st_w2,
                        const float* __restrict__ ro_w1,
                        unsigned short* __restrict__ me1T, unsigned short* __restrict__ me2T,
                        unsigned short* __restrict__ mn1T, unsigned short* __restrict__ mn2T,
                        unsigned short* __restrict__ st1T, unsigned short* __restrict__ st2T,
                        unsigned short* __restrict__ ro1T) {
    int gid = blockIdx.x * 256 + threadIdx.x;
    const int S1 = Ll * 256 * EKPAD;
    if (gid < S1) {
        int i = gid / (256 * EKPAD);
        int r = gid % (256 * EKPAD);
        int n = r / EKPAD, k = r % EKPAD;
        float v = (k < EDGE) ? me_w1[(i * EDGE + k) * 256 + n] : 0.f;
        me1T[gid] = f2b(v);
        return;
    }
    gid -= S1;
    const int S2 = Ll * 256 * 256;
    const float* srcs[5] = { me_w2, mn_w1, mn_w2, st_w1, st_w2 };
    unsigned short* dsts[5] = { me2T, mn1T, mn2T, st1T, st2T };
#pragma unroll
    for (int q = 0; q < 5; ++q) {
        if (gid < S2) {
            int i = gid >> 16;
            int r = gid & 65535;
            int n = r >> 8, k = r & 255;
            dsts[q][gid] = f2b(srcs[q][(i << 16) + k * 256 + n]);
            return;
        }
        gid -= S2;
    }
    int n = gid >> 8, k = gid & 255;
    ro1T[gid] = f2b(ro_w1[k * 256 + n]);
}

__global__ void k_readout(const unsigned short* __restrict__ t, const float* __restrict__ w2,
                          const float* __restrict__ b2, const int* __restrict__ num_nodes,
                          const float* __restrict__ evw, const float* __restrict__ evb,
                          float* __restrict__ out) {
    __shared__ float red[256];
    int b = blockIdx.x, tid = threadIdx.x;
    const unsigned short* tb = t + (long)b * Nn * 256;
    float part = 0.f;
    for (int i = tid; i < Nn * 256; i += 256)
        part += b2f(tb[i]) * w2[i & 255];
    red[tid] = part;
    __syncthreads();
    for (int d = 128; d > 0; d >>= 1) {
        if (tid < d) red[tid] += red[tid + d];
        __syncthreads();
    }
    if (tid == 0) {
        float g = red[0] + (float)Nn * b2[0];
        g = g * 2.0f + (-1.5f) * (float)num_nodes[b];
        out[b * 4 + 0] = g * evw[0] + evb[0];
        out[b * 4 + 1] = spf(g * evw[1] + evb[1]);
        out[b * 4 + 2] = spf(g * evw[2] + evb[2]) + 1.f;
        out[b * 4 + 3] = spf(g * evw[3] + evb[3]);
    }
}

// ---------------- workspace layout ----------------
constexpr size_t al(size_t x) { return (x + 255) & ~(size_t)255; }
constexpr size_t O_OFF    = 0;
constexpr size_t O_GSRC   = al(O_OFF + 65 * 4);
constexpr size_t O_GDST   = al(O_GSRC + (size_t)TE * 4);
constexpr size_t O_CNT    = al(O_GDST + (size_t)TE * 4);
constexpr size_t O_COFF   = al(O_CNT + (size_t)TN * 4);
constexpr size_t O_POS    = al(O_COFF + (size_t)(TN + 1) * 4);
constexpr size_t O_GSRCS  = al(O_POS + (size_t)TN * 4);
constexpr size_t O_DCSR   = al(O_GSRCS + (size_t)TE * 4);
constexpr size_t O_RBFG   = al(O_DCSR + (size_t)TE * 4);
constexpr size_t O_TTAB   = al(O_RBFG + (size_t)TABN * EKPAD * 2);
constexpr size_t O_GTAB   = al(O_TTAB + (size_t)Ll * TABN * 256 * 2);
constexpr size_t O_ME1T   = al(O_GTAB + (size_t)Ll * TABN * 256 * 2);
constexpr size_t O_ME2T   = al(O_ME1T + (size_t)Ll * 256 * EKPAD * 2);
constexpr size_t O_MN1T   = al(O_ME2T + (size_t)Ll * 256 * 256 * 2);
constexpr size_t O_MN2T   = al(O_MN1T + (size_t)Ll * 256 * 256 * 2);
constexpr size_t O_ST1T   = al(O_MN2T + (size_t)Ll * 256 * 256 * 2);
constexpr size_t O_ST2T   = al(O_ST1T + (size_t)Ll * 256 * 256 * 2);
constexpr size_t O_RO1T   = al(O_ST2T + (size_t)Ll * 256 * 256 * 2);
constexpr size_t O_X      = al(O_RO1T + (size_t)256 * 256 * 2);
constexpr size_t O_XB     = al(O_X + (size_t)TN * 256 * 4);
constexpr size_t O_TMPB   = al(O_XB + (size_t)TN * 256 * 2);
constexpr size_t O_NMSG   = al(O_TMPB + (size_t)TN * 256 * 2);
constexpr size_t WS_NEED  = al(O_NMSG + (size_t)TN * 256 * 2);

extern "C" void kernel_launch(void* const* d_in, const int* in_sizes, int n_in,
                              void* d_out, int out_size, void* d_ws, size_t ws_size,
                              hipStream_t stream) {
    if (ws_size < WS_NEED) return;

    const int*   nodes     = (const int*)d_in[0];
    const int*   num_nodes = (const int*)d_in[1];
    const int*   edges     = (const int*)d_in[2];
    const float* efeat     = (const float*)d_in[3];
    const float* embed     = (const float*)d_in[5];
    const float* me_w1 = (const float*)d_in[6],  *me_b1 = (const float*)d_in[7];
    const float* me_w2 = (const float*)d_in[8],  *me_b2 = (const float*)d_in[9];
    const float* mn_w1 = (const float*)d_in[10], *mn_b1 = (const float*)d_in[11];
    const float* mn_w2 = (const float*)d_in[12], *mn_b2 = (const float*)d_in[13];
    const float* st_w1 = (const float*)d_in[14], *st_b1 = (const float*)d_in[15];
    const float* st_w2 = (const float*)d_in[16], *st_b2 = (const float*)d_in[17];
    const float* ro_w1 = (const float*)d_in[18], *ro_b1 = (const float*)d_in[19];
    const float* ro_w2 = (const float*)d_in[20], *ro_b2 = (const float*)d_in[21];
    const float* ev_w  = (const float*)d_in[22], *ev_b  = (const float*)d_in[23];

    char* ws = (char*)d_ws;
    int* off   = (int*)(ws + O_OFF);
    int* gsrc  = (int*)(ws + O_GSRC);
    int* gdst  = (int*)(ws + O_GDST);
    int* cnt   = (int*)(ws + O_CNT);
    int* coff  = (int*)(ws + O_COFF);
    int* pos   = (int*)(ws + O_POS);
    int* gsrcs = (int*)(ws + O_GSRCS);
    float* dcsr = (float*)(ws + O_DCSR);
    unsigned short* rbfg  = (unsigned short*)(ws + O_RBFG);
    unsigned short* ttab  = (unsigned short*)(ws + O_TTAB);
    unsigned short* gtab  = (unsigned short*)(ws + O_GTAB);
    unsigned short* me1T  = (unsigned short*)(ws + O_ME1T);
    unsigned short* me2T  = (unsigned short*)(ws + O_ME2T);
    unsigned short* mn1T  = (unsigned short*)(ws + O_MN1T);
    unsigned short* mn2T  = (unsigned short*)(ws + O_MN2T);
    unsigned short* st1T  = (unsigned short*)(ws + O_ST1T);
    unsigned short* st2T  = (unsigned short*)(ws + O_ST2T);
    unsigned short* ro1T  = (unsigned short*)(ws + O_RO1T);
    float*          x     = (float*)(ws + O_X);
    unsigned short* xb    = (unsigned short*)(ws + O_XB);
    unsigned short* tmpb  = (unsigned short*)(ws + O_TMPB);
    unsigned short* nmsgb = (unsigned short*)(ws + O_NMSG);
    float* out = (float*)d_out;

    hipMemsetAsync(cnt, 0, TN * 4, stream);
    k_offsets<<<1, Bb, 0, stream>>>(num_nodes, off);
    k_edgeprep<<<TE / 256, 256, 0, stream>>>(edges, off, gsrc, gdst, cnt);
    k_scan<<<1, 1024, 0, stream>>>(cnt, coff, pos);
    k_fill<<<TE / 256, 256, 0, stream>>>(gdst, gsrc, efeat, pos, gsrcs, dcsr);
    k_rbfgrid<<<(TABN * EKPAD) / 256, 256, 0, stream>>>(rbfg);
    k_embed<<<TN, 256, 0, stream>>>(nodes, embed, x, xb);
    {
        const int total = Ll * 256 * EKPAD + 5 * Ll * 256 * 256 + 256 * 256;
        k_wprep<<<total / 256, 256, 0, stream>>>(me_w1, me_w2, mn_w1, mn_w2, st_w1, st_w2, ro_w1,
                                                 me1T, me2T, mn1T, mn2T, st1T, st2T, ro1T);
    }

    // ---- build all 6 layers' gate tables (z = layer) ----
    const dim3 gT(2, TABN / 128, Ll), gN(2, TN / 64, 1), blk(256);
    gemm_k<1, 0, 128><<<gT, blk, 0, stream>>>(rbfg, me1T, me_b1, ttab, nullptr, nullptr,
                                              TABN, EKPAD,
                                              0, 256 * EKPAD, 256, (long)TABN * 256);
    gemm_k<0, 0, 128><<<gT, blk, 0, stream>>>(ttab, me2T, me_b2, gtab, nullptr, nullptr,
                                              TABN, 256,
                                              (long)TABN * 256, 65536, 256, (long)TABN * 256);

    for (int i = 0; i < Ll; ++i) {
        fused_node16<0, 0><<<TN / 16, 256, 0, stream>>>(
            xb, mn1T + i * 65536, mn_b1 + i * 256,
            mn2T + i * 65536, mn_b2 + i * 256, nmsgb, nullptr, nullptr,
            nullptr, nullptr, nullptr, nullptr, nullptr);
        fused_node16<2, 1><<<TN / 16, 256, 0, stream>>>(
            nullptr, st1T + i * 65536, st_b1 + i * 256,
            st2T + i * 65536, st_b2 + i * 256, nullptr, x, xb,
            dcsr, gtab + (size_t)i * TABN * 256, nmsgb, coff, gsrcs);
    }

    gemm_k<1, 0, 64><<<gN, blk, 0, stream>>>(xb, ro1T, ro_b1, tmpb, nullptr, nullptr,
                                             TN, 256, 0, 0, 0, 0);
    k_readout<<<Bb, 256, 0, stream>>>(tmpb, ro_w2, ro_b2, num_nodes, ev_w, ev_b, out);
}

// Round 14
// 456.954 us; speedup vs baseline: 3.0686x; 1.0434x over previous
//
#include <hip/hip_runtime.h>

#define Bb 64
#define Nn 128
#define Ee 2048
#define Hh 256
#define Ll 6
#define TN 8192
#define TE 131072
#define EDGE 50
#define EKPAD 64
#define TABN 512
#define TSCALE ((float)(TABN - 2) / 5.0f)

typedef __attribute__((ext_vector_type(4))) float f32x4;
typedef __attribute__((ext_vector_type(8))) __bf16 bf16x8;
typedef __attribute__((ext_vector_type(8))) unsigned short ushort8;

__device__ inline float b2f(unsigned short u) {
    union { unsigned u; float f; } v; v.u = ((unsigned)u) << 16; return v.f;
}
__device__ inline unsigned short f2b(float f) {
    union { float f; unsigned u; } v; v.f = f;
    unsigned r = v.u + 0x7fffu + ((v.u >> 16) & 1u);
    return (unsigned short)(r >> 16);
}
__device__ inline float spf(float x) {
    return fmaxf(x, 0.f) + __logf(1.f + __expf(-fabsf(x)));
}
__device__ inline float sspf(float x) {
    return spf(x) - 0.69314718055994530942f;
}

// ---------------- GEMM (R4-verified) + z-batch strides ----------------
template <int ACT, int OUTMODE, int TM>
__global__ __launch_bounds__(256)
void gemm_k(const unsigned short* __restrict__ A,
            const unsigned short* __restrict__ WT,
            const float* __restrict__ bias,
            unsigned short* __restrict__ Cb,
            float* __restrict__ Xf,
            unsigned short* __restrict__ Xb,
            int M, int K,
            long Az, long Wz, long bz, long Cz)
{
    constexpr int BK  = 64;
    constexpr int TNc = 128;
    constexpr int MR  = TM / 32;
    constexpr int NR  = 4;
    constexpr int STAGE_B = (TM + TNc) * BK * 2;
    constexpr int EPI_B   = (OUTMODE == 2) ? TM * TNc * 4 : TM * TNc * 2;
    constexpr int SMEM_B  = STAGE_B > EPI_B ? STAGE_B : EPI_B;

    __shared__ __align__(16) unsigned char smem[SMEM_B];
    unsigned short* As = (unsigned short*)smem;
    unsigned short* Bs = As + TM * BK;

    const int z = blockIdx.z;
    A += z * Az; WT += z * Wz; bias += z * bz;
    if (Cb) Cb += z * Cz;

    const int tid  = threadIdx.x;
    const int lane = tid & 63;
    const int w    = tid >> 6;
    const int wr   = w >> 1, wc = w & 1;
    const int r16  = lane & 15;
    const int kg   = lane >> 4;

    const long brow = (long)blockIdx.y * TM;
    const int  bcol = blockIdx.x * TNc;

    constexpr int ACH = TM / 8;
    constexpr int NCH = ACH + TNc / 8;
    constexpr int IPW = NCH / 4;
    const int lrow  = lane >> 3;
    const int lslot = lane & 7;

    f32x4 acc[MR][NR];
#pragma unroll
    for (int m = 0; m < MR; ++m)
#pragma unroll
        for (int n = 0; n < NR; ++n) acc[m][n] = f32x4{0.f, 0.f, 0.f, 0.f};

    for (int k0 = 0; k0 < K; k0 += BK) {
        __syncthreads();
#pragma unroll
        for (int i = 0; i < IPW; ++i) {
            const int c    = w * IPW + i;
            const bool isA = c < ACH;
            const int cc   = isA ? c : c - ACH;
            const int srow = cc * 8 + lrow;
            const int kch  = lslot ^ (srow & 7);
            const unsigned short* gp = isA
                ? A  + (brow + srow) * (long)K + k0 + kch * 8
                : WT + (bcol + srow) * (long)K + k0 + kch * 8;
            unsigned short* lp = (isA ? As : Bs) + cc * 512;
            __builtin_amdgcn_global_load_lds(
                (const __attribute__((address_space(1))) void*)gp,
                (__attribute__((address_space(3))) void*)lp, 16, 0, 0);
        }
        __syncthreads();

        bf16x8 a[MR][2], b[NR][2];
#pragma unroll
        for (int m = 0; m < MR; ++m) {
            const int row = wr * (MR * 16) + m * 16 + r16;
            const unsigned short* base = As + row * BK;
#pragma unroll
            for (int kk = 0; kk < 2; ++kk) {
                const int slot = (kk * 4 + kg) ^ (row & 7);
                a[m][kk] = *(const bf16x8*)(base + slot * 8);
            }
        }
#pragma unroll
        for (int n = 0; n < NR; ++n) {
            const int row = wc * 64 + n * 16 + r16;
            const unsigned short* base = Bs + row * BK;
#pragma unroll
            for (int kk = 0; kk < 2; ++kk) {
                const int slot = (kk * 4 + kg) ^ (row & 7);
                b[n][kk] = *(const bf16x8*)(base + slot * 8);
            }
        }
#pragma unroll
        for (int kk = 0; kk < 2; ++kk)
#pragma unroll
            for (int m = 0; m < MR; ++m)
#pragma unroll
                for (int n = 0; n < NR; ++n)
                    acc[m][n] = __builtin_amdgcn_mfma_f32_16x16x32_bf16(
                        b[n][kk], a[m][kk], acc[m][n], 0, 0, 0);
    }

    __syncthreads();

    if (OUTMODE != 2) {
#pragma unroll
        for (int m = 0; m < MR; ++m) {
            const int row = wr * (MR * 16) + m * 16 + r16;
#pragma unroll
            for (int n = 0; n < NR; ++n) {
                const int colL = wc * 64 + n * 16 + kg * 4;
                const f32x4 bv = *(const f32x4*)(bias + bcol + colL);
                float v0 = acc[m][n][0] + bv[0];
                float v1 = acc[m][n][1] + bv[1];
                float v2 = acc[m][n][2] + bv[2];
                float v3 = acc[m][n][3] + bv[3];
                if (ACT) { v0 = sspf(v0); v1 = sspf(v1); v2 = sspf(v2); v3 = sspf(v3); }
                uint2 p;
                p.x = (unsigned)f2b(v0) | ((unsigned)f2b(v1) << 16);
                p.y = (unsigned)f2b(v2) | ((unsigned)f2b(v3) << 16);
                const int off = (row * 256 + colL * 2) ^ ((row & 7) << 4);
                *(uint2*)(smem + off) = p;
            }
        }
        __syncthreads();
        constexpr int ITER = TM / 16;
#pragma unroll
        for (int q = 0; q < ITER; ++q) {
            const int flat = q * 4096 + tid * 16;
            const int row = flat >> 8, cbyte = flat & 255;
            uint4 d = *(const uint4*)(smem + ((row * 256 + cbyte) ^ ((row & 7) << 4)));
            *(uint4*)((unsigned char*)Cb + (brow + row) * 512 + bcol * 2 + cbyte) = d;
        }
    } else {
#pragma unroll
        for (int m = 0; m < MR; ++m) {
            const int row = wr * (MR * 16) + m * 16 + r16;
#pragma unroll
            for (int n = 0; n < NR; ++n) {
                const int colL = wc * 64 + n * 16 + kg * 4;
                const f32x4 bv = *(const f32x4*)(bias + bcol + colL);
                f32x4 v = acc[m][n] + bv;
                const int off = (row * 512 + colL * 4) ^ ((row & 7) << 4);
                *(f32x4*)(smem + off) = v;
            }
        }
        __syncthreads();
        constexpr int ITER = TM / 8;
#pragma unroll
        for (int q = 0; q < ITER; ++q) {
            const int flat = q * 4096 + tid * 16;
            const int row = flat >> 9, cbyte = flat & 511;
            f32x4 v = *(const f32x4*)(smem + ((row * 512 + cbyte) ^ ((row & 7) << 4)));
            const long base = (brow + row) * 256 + bcol + (cbyte >> 2);
            f32x4 xo = *(const f32x4*)(Xf + base);
            f32x4 nx = xo + v;
            *(f32x4*)(Xf + base) = nx;
            uint2 p;
            p.x = (unsigned)f2b(nx[0]) | ((unsigned)f2b(nx[1]) << 16);
            p.y = (unsigned)f2b(nx[2]) | ((unsigned)f2b(nx[3]) << 16);
            *(uint2*)(Xb + base) = p;
        }
    }
}

// ======== fused node MLP, 16-row tiles (R13-verified) ========
template <int OUTMODE, int AGG>
__global__ __launch_bounds__(256, 2)
void fused_node16(const unsigned short* __restrict__ Ab,
                  const unsigned short* __restrict__ W1T,
                  const float* __restrict__ b1,
                  const unsigned short* __restrict__ W2T,
                  const float* __restrict__ b2,
                  unsigned short* __restrict__ Cb,
                  float* __restrict__ Xf,
                  unsigned short* __restrict__ Xb,
                  const float* __restrict__ dcsr,
                  const unsigned short* __restrict__ tab,
                  const unsigned short* __restrict__ nmsgb,
                  const int* __restrict__ coff,
                  const int* __restrict__ gsrcs)
{
    __shared__ __align__(16) unsigned char smem[16384];       // A(8K) + t(8K)
    unsigned short* A_lds = (unsigned short*)smem;            // 16 x 256 bf16
    unsigned char*  t_lds = smem + 8192;                      // 16 x 256 bf16

    const int tid  = threadIdx.x;
    const int lane = tid & 63;
    const int w    = tid >> 6;            // 4 waves; wave w: cols [w*64, w*64+64)
    const int r16  = lane & 15;
    const int kg   = lane >> 4;
    const long brow = (long)blockIdx.x * 16;

    if (!AGG) {
        const int lrow  = lane >> 5;
        const int lslot = lane & 31;
#pragma unroll
        for (int i = 0; i < 2; ++i) {
            const int cc   = w * 2 + i;
            const int srow = cc * 2 + lrow;
            const int kch  = lslot ^ (srow & 7);
            const unsigned short* gp = Ab + (brow + srow) * 256 + kch * 8;
            __builtin_amdgcn_global_load_lds(
                (const __attribute__((address_space(1))) void*)gp,
                (__attribute__((address_space(3))) void*)(A_lds + cc * 512), 16, 0, 0);
        }
    } else {
        // in-kernel aggregation (R11-verified lerp math): node = tid>>4, 16 ch/thread
        const int node = tid >> 4;
        const int c0   = (tid & 15) * 16;
        const int gn   = (int)brow + node;
        float s[16];
#pragma unroll
        for (int j = 0; j < 16; ++j) s[j] = 0.f;
        const int beg = coff[gn], end = coff[gn + 1];
        for (int i = beg; i < end; ++i) {
            const float d  = dcsr[i];
            const int   sr = gsrcs[i];
            const float xx = d * TSCALE;
            const int   i0 = (int)xx;
            const float f  = xx - (float)i0;
            const unsigned short* t0 = tab + (long)i0 * 256 + c0;
            ushort8 g0a = *(const ushort8*)t0;
            ushort8 g0b = *(const ushort8*)(t0 + 8);
            ushort8 g1a = *(const ushort8*)(t0 + 256);
            ushort8 g1b = *(const ushort8*)(t0 + 264);
            const unsigned short* np = nmsgb + ((long)sr << 8) + c0;
            ushort8 na = *(const ushort8*)np;
            ushort8 nb = *(const ushort8*)(np + 8);
#pragma unroll
            for (int j = 0; j < 8; ++j) {
                float a = b2f(g0a[j]);
                s[j] += (a + (b2f(g1a[j]) - a) * f) * b2f(na[j]);
            }
#pragma unroll
            for (int j = 0; j < 8; ++j) {
                float a = b2f(g0b[j]);
                s[8 + j] += (a + (b2f(g1b[j]) - a) * f) * b2f(nb[j]);
            }
        }
        const int swzn = (node & 7) << 4;
#pragma unroll
        for (int j = 0; j < 4; ++j) {
            uint2 p;
            p.x = (unsigned)f2b(s[j * 4 + 0]) | ((unsigned)f2b(s[j * 4 + 1]) << 16);
            p.y = (unsigned)f2b(s[j * 4 + 2]) | ((unsigned)f2b(s[j * 4 + 3]) << 16);
            const int c = c0 + j * 4;
            *(uint2*)((unsigned char*)A_lds + ((node * 512 + c * 2) ^ swzn)) = p;
        }
    }
    __syncthreads();

    const int arow = r16;
    const int swz  = (arow & 7) << 4;

    // ---- GEMM1 ----
    f32x4 acc1[4];
#pragma unroll
    for (int n = 0; n < 4; ++n) acc1[n] = f32x4{0.f, 0.f, 0.f, 0.f};
#pragma unroll
    for (int kk = 0; kk < 8; ++kk) {
        const int slot = (kk * 4 + kg) ^ (arow & 7);
        bf16x8 af = *(const bf16x8*)(A_lds + arow * 256 + slot * 8);
#pragma unroll
        for (int n = 0; n < 4; ++n) {
            const int col = w * 64 + n * 16 + r16;
            bf16x8 wf = *(const bf16x8*)(W1T + col * 256 + kk * 32 + kg * 8);
            acc1[n] = __builtin_amdgcn_mfma_f32_16x16x32_bf16(wf, af, acc1[n], 0, 0, 0);
        }
    }
#pragma unroll
    for (int n = 0; n < 4; ++n) {
        const int c0 = w * 64 + n * 16 + kg * 4;
        const f32x4 bv = *(const f32x4*)(b1 + c0);
        uint2 p;
        p.x = (unsigned)f2b(sspf(acc1[n][0] + bv[0])) |
              ((unsigned)f2b(sspf(acc1[n][1] + bv[1])) << 16);
        p.y = (unsigned)f2b(sspf(acc1[n][2] + bv[2])) |
              ((unsigned)f2b(sspf(acc1[n][3] + bv[3])) << 16);
        *(uint2*)(t_lds + ((arow * 512 + c0 * 2) ^ swz)) = p;
    }
    __syncthreads();

    // ---- GEMM2 ----
    f32x4 acc2[4];
#pragma unroll
    for (int n = 0; n < 4; ++n) acc2[n] = f32x4{0.f, 0.f, 0.f, 0.f};
#pragma unroll
    for (int kk = 0; kk < 8; ++kk) {
        bf16x8 af = *(const bf16x8*)(t_lds + ((arow * 512 + kk * 64 + kg * 16) ^ swz));
#pragma unroll
        for (int n = 0; n < 4; ++n) {
            const int col = w * 64 + n * 16 + r16;
            bf16x8 wf = *(const bf16x8*)(W2T + col * 256 + kk * 32 + kg * 8);
            acc2[n] = __builtin_amdgcn_mfma_f32_16x16x32_bf16(wf, af, acc2[n], 0, 0, 0);
        }
    }
    __syncthreads();

    if (OUTMODE == 0) {
#pragma unroll
        for (int n = 0; n < 4; ++n) {
            const int c0 = w * 64 + n * 16 + kg * 4;
            const f32x4 bv = *(const f32x4*)(b2 + c0);
            uint2 p;
            p.x = (unsigned)f2b(acc2[n][0] + bv[0]) | ((unsigned)f2b(acc2[n][1] + bv[1]) << 16);
            p.y = (unsigned)f2b(acc2[n][2] + bv[2]) | ((unsigned)f2b(acc2[n][3] + bv[3]) << 16);
            *(uint2*)(smem + ((arow * 512 + c0 * 2) ^ swz)) = p;
        }
        __syncthreads();
#pragma unroll
        for (int q = 0; q < 2; ++q) {
            const int flat = q * 4096 + tid * 16;
            const int row = flat >> 9, cbyte = flat & 511;
            uint4 d = *(const uint4*)(smem + ((row * 512 + cbyte) ^ ((row & 7) << 4)));
            *(uint4*)((unsigned char*)Cb + (brow + row) * 512 + cbyte) = d;
        }
    } else {
#pragma unroll
        for (int n = 0; n < 4; ++n) {
            const int c0 = w * 64 + n * 16 + kg * 4;
            const f32x4 bv = *(const f32x4*)(b2 + c0);
            f32x4 v = acc2[n] + bv;
            *(f32x4*)(smem + ((arow * 1024 + c0 * 4) ^ swz)) = v;
        }
        __syncthreads();
#pragma unroll
        for (int q = 0; q < 4; ++q) {
            const int flat = q * 4096 + tid * 16;
            const int row = flat >> 10, cbyte = flat & 1023;
            f32x4 v = *(const f32x4*)(smem + ((row * 1024 + cbyte) ^ ((row & 7) << 4)));
            const long base = (brow + row) * 256 + (cbyte >> 2);
            f32x4 xo = *(const f32x4*)(Xf + base);
            f32x4 nx = xo + v;
            *(f32x4*)(Xf + base) = nx;
            uint2 p;
            p.x = (unsigned)f2b(nx[0]) | ((unsigned)f2b(nx[1]) << 16);
            p.y = (unsigned)f2b(nx[2]) | ((unsigned)f2b(nx[3]) << 16);
            *(uint2*)(Xb + base) = p;
        }
    }
}

// ---------------- small kernels ----------------
__global__ void k_offsets(const int* __restrict__ num_nodes, int* __restrict__ off) {
    __shared__ int s[Bb];
    int t = threadIdx.x;
    s[t] = num_nodes[t];
    __syncthreads();
    for (int d = 1; d < Bb; d <<= 1) {
        int v = (t >= d) ? s[t - d] : 0;
        __syncthreads();
        s[t] += v;
        __syncthreads();
    }
    off[t + 1] = s[t];
    if (t == 0) off[0] = 0;
}

__global__ void k_edgeprep(const int* __restrict__ edges, const int* __restrict__ off,
                           int* __restrict__ gsrc, int* __restrict__ gdst, int* __restrict__ cnt) {
    int ge = blockIdx.x * 256 + threadIdx.x;
    if (ge >= TE) return;
    int b = ge >> 11;
    int o = off[b];
    gsrc[ge] = edges[ge * 2 + 0] + o;
    int d = edges[ge * 2 + 1] + o;
    gdst[ge] = d;
    atomicAdd(&cnt[d], 1);
}

__global__ void k_scan(const int* __restrict__ cnt, int* __restrict__ coff, int* __restrict__ pos) {
    __shared__ int part[1024];
    int t = threadIdx.x;
    int loc[8];
    int s = 0;
#pragma unroll
    for (int j = 0; j < 8; ++j) { loc[j] = cnt[t * 8 + j]; s += loc[j]; }
    part[t] = s;
    __syncthreads();
    for (int d = 1; d < 1024; d <<= 1) {
        int v = (t >= d) ? part[t - d] : 0;
        __syncthreads();
        part[t] += v;
        __syncthreads();
    }
    int base = part[t] - s;
#pragma unroll
    for (int j = 0; j < 8; ++j) {
        int idx = t * 8 + j;
        coff[idx] = base;
        pos[idx]  = base;
        base += loc[j];
    }
    if (t == 1023) coff[TN] = part[1023];
}

__global__ void k_fill(const int* __restrict__ gdst, const int* __restrict__ gsrc,
                       const float* __restrict__ ef,
                       int* __restrict__ pos, int* __restrict__ gsrcs,
                       float* __restrict__ dcsr) {
    int ge = blockIdx.x * 256 + threadIdx.x;
    if (ge >= TE) return;
    int d = gdst[ge];
    int p = atomicAdd(&pos[d], 1);
    gsrcs[p] = gsrc[ge];
    dcsr[p]  = ef[ge];
}

__global__ void k_rbfgrid(unsigned short* __restrict__ rbfg) {
    int gid = blockIdx.x * 256 + threadIdx.x;   // TABN * 64
    int i = gid >> 6, k = gid & 63;
    float v = 0.f;
    if (k < EDGE) {
        float d = (float)i / TSCALE;
        float t = d - 0.1f * (float)k;
        v = __expf(-50.f * t * t);
    }
    rbfg[gid] = f2b(v);
}

__global__ void k_embed(const int* __restrict__ nodes, const float* __restrict__ embed,
                        float* __restrict__ x, unsigned short* __restrict__ xb) {
    int gid = blockIdx.x * 256 + threadIdx.x;
    int i = gid >> 8, c = gid & 255;
    float v = embed[(nodes[i] << 8) + c];
    x[gid] = v;
    xb[gid] = f2b(v);
}

__global__ void k_wprep(const float* __restrict__ me_w1, const float* __restrict__ me_w2,
                        const float* __restrict__ mn_w1, const float* __restrict__ mn_w2,
                        const float* __restrict__ st_w1, const float* __restrict__ st_w2,
                        const float* __restrict__ ro_w1,
                        unsigned short* __restrict__ me1T, unsigned short* __restrict__ me2T,
                        unsigned short* __restrict__ mn1T, unsigned short* __restrict__ mn2T,
                        unsigned short* __restrict__ st1T, unsigned short* __restrict__ st2T,
                        unsigned short* __restrict__ ro1T) {
    int gid = blockIdx.x * 256 + threadIdx.x;
    const int S1 = Ll * 256 * EKPAD;
    if (gid < S1) {
        int i = gid / (256 * EKPAD);
        int r = gid % (256 * EKPAD);
        int n = r / EKPAD, k = r % EKPAD;
        float v = (k < EDGE) ? me_w1[(i * EDGE + k) * 256 + n] : 0.f;
        me1T[gid] = f2b(v);
        return;
    }
    gid -= S1;
    const int S2 = Ll * 256 * 256;
    const float* srcs[5] = { me_w2, mn_w1, mn_w2, st_w1, st_w2 };
    unsigned short* dsts[5] = { me2T, mn1T, mn2T, st1T, st2T };
#pragma unroll
    for (int q = 0; q < 5; ++q) {
        if (gid < S2) {
            int i = gid >> 16;
            int r = gid & 65535;
            int n = r >> 8, k = r & 255;
            dsts[q][gid] = f2b(srcs[q][(i << 16) + k * 256 + n]);
            return;
        }
        gid -= S2;
    }
    int n = gid >> 8, k = gid & 255;
    ro1T[gid] = f2b(ro_w1[k * 256 + n]);
}

__global__ void k_readout(const unsigned short* __restrict__ t, const float* __restrict__ w2,
                          const float* __restrict__ b2, const int* __restrict__ num_nodes,
                          const float* __restrict__ evw, const float* __restrict__ evb,
                          float* __restrict__ out) {
    __shared__ float red[256];
    int b = blockIdx.x, tid = threadIdx.x;
    const unsigned short* tb = t + (long)b * Nn * 256;
    float part = 0.f;
    for (int i = tid; i < Nn * 256; i += 256)
        part += b2f(tb[i]) * w2[i & 255];
    red[tid] = part;
    __syncthreads();
    for (int d = 128; d > 0; d >>= 1) {
        if (tid < d) red[tid] += red[tid + d];
        __syncthreads();
    }
    if (tid == 0) {
        float g = red[0] + (float)Nn * b2[0];
        g = g * 2.0f + (-1.5f) * (float)num_nodes[b];
        out[b * 4 + 0] = g * evw[0] + evb[0];
        out[b * 4 + 1] = spf(g * evw[1] + evb[1]);
        out[b * 4 + 2] = spf(g * evw[2] + evb[2]) + 1.f;
        out[b * 4 + 3] = spf(g * evw[3] + evb[3]);
    }
}

// ---------------- workspace layout ----------------
constexpr size_t al(size_t x) { return (x + 255) & ~(size_t)255; }
constexpr size_t O_OFF    = 0;
constexpr size_t O_GSRC   = al(O_OFF + 65 * 4);
constexpr size_t O_GDST   = al(O_GSRC + (size_t)TE * 4);
constexpr size_t O_CNT    = al(O_GDST + (size_t)TE * 4);
constexpr size_t O_COFF   = al(O_CNT + (size_t)TN * 4);
constexpr size_t O_POS    = al(O_COFF + (size_t)(TN + 1) * 4);
constexpr size_t O_GSRCS  = al(O_POS + (size_t)TN * 4);
constexpr size_t O_DCSR   = al(O_GSRCS + (size_t)TE * 4);
constexpr size_t O_RBFG   = al(O_DCSR + (size_t)TE * 4);
constexpr size_t O_TTAB   = al(O_RBFG + (size_t)TABN * EKPAD * 2);
constexpr size_t O_GTAB   = al(O_TTAB + (size_t)Ll * TABN * 256 * 2);
constexpr size_t O_ME1T   = al(O_GTAB + (size_t)Ll * TABN * 256 * 2);
constexpr size_t O_ME2T   = al(O_ME1T + (size_t)Ll * 256 * EKPAD * 2);
constexpr size_t O_MN1T   = al(O_ME2T + (size_t)Ll * 256 * 256 * 2);
constexpr size_t O_MN2T   = al(O_MN1T + (size_t)Ll * 256 * 256 * 2);
constexpr size_t O_ST1T   = al(O_MN2T + (size_t)Ll * 256 * 256 * 2);
constexpr size_t O_ST2T   = al(O_ST1T + (size_t)Ll * 256 * 256 * 2);
constexpr size_t O_RO1T   = al(O_ST2T + (size_t)Ll * 256 * 256 * 2);
constexpr size_t O_X      = al(O_RO1T + (size_t)256 * 256 * 2);
constexpr size_t O_XB     = al(O_X + (size_t)TN * 256 * 4);
constexpr size_t O_TMPB   = al(O_XB + (size_t)TN * 256 * 2);
constexpr size_t O_NMSG   = al(O_TMPB + (size_t)TN * 256 * 2);
constexpr size_t WS_NEED  = al(O_NMSG + (size_t)TN * 256 * 2);

extern "C" void kernel_launch(void* const* d_in, const int* in_sizes, int n_in,
                              void* d_out, int out_size, void* d_ws, size_t ws_size,
                              hipStream_t stream) {
    if (ws_size < WS_NEED) return;

    const int*   nodes     = (const int*)d_in[0];
    const int*   num_nodes = (const int*)d_in[1];
    const int*   edges     = (const int*)d_in[2];
    const float* efeat     = (const float*)d_in[3];
    const float* embed     = (const float*)d_in[5];
    const float* me_w1 = (const float*)d_in[6],  *me_b1 = (const float*)d_in[7];
    const float* me_w2 = (const float*)d_in[8],  *me_b2 = (const float*)d_in[9];
    const float* mn_w1 = (const float*)d_in[10], *mn_b1 = (const float*)d_in[11];
    const float* mn_w2 = (const float*)d_in[12], *mn_b2 = (const float*)d_in[13];
    const float* st_w1 = (const float*)d_in[14], *st_b1 = (const float*)d_in[15];
    const float* st_w2 = (const float*)d_in[16], *st_b2 = (const float*)d_in[17];
    const float* ro_w1 = (const float*)d_in[18], *ro_b1 = (const float*)d_in[19];
    const float* ro_w2 = (const float*)d_in[20], *ro_b2 = (const float*)d_in[21];
    const float* ev_w  = (const float*)d_in[22], *ev_b  = (const float*)d_in[23];

    char* ws = (char*)d_ws;
    int* off   = (int*)(ws + O_OFF);
    int* gsrc  = (int*)(ws + O_GSRC);
    int* gdst  = (int*)(ws + O_GDST);
    int* cnt   = (int*)(ws + O_CNT);
    int* coff  = (int*)(ws + O_COFF);
    int* pos   = (int*)(ws + O_POS);
    int* gsrcs = (int*)(ws + O_GSRCS);
    float* dcsr = (float*)(ws + O_DCSR);
    unsigned short* rbfg  = (unsigned short*)(ws + O_RBFG);
    unsigned short* ttab  = (unsigned short*)(ws + O_TTAB);
    unsigned short* gtab  = (unsigned short*)(ws + O_GTAB);
    unsigned short* me1T  = (unsigned short*)(ws + O_ME1T);
    unsigned short* me2T  = (unsigned short*)(ws + O_ME2T);
    unsigned short* mn1T  = (unsigned short*)(ws + O_MN1T);
    unsigned short* mn2T  = (unsigned short*)(ws + O_MN2T);
    unsigned short* st1T  = (unsigned short*)(ws + O_ST1T);
    unsigned short* st2T  = (unsigned short*)(ws + O_ST2T);
    unsigned short* ro1T  = (unsigned short*)(ws + O_RO1T);
    float*          x     = (float*)(ws + O_X);
    unsigned short* xb    = (unsigned short*)(ws + O_XB);
    unsigned short* tmpb  = (unsigned short*)(ws + O_TMPB);
    unsigned short* nmsgb = (unsigned short*)(ws + O_NMSG);
    float* out = (float*)d_out;

    hipMemsetAsync(cnt, 0, TN * 4, stream);
    k_offsets<<<1, Bb, 0, stream>>>(num_nodes, off);
    k_edgeprep<<<TE / 256, 256, 0, stream>>>(edges, off, gsrc, gdst, cnt);
    k_scan<<<1, 1024, 0, stream>>>(cnt, coff, pos);
    k_fill<<<TE / 256, 256, 0, stream>>>(gdst, gsrc, efeat, pos, gsrcs, dcsr);
    k_rbfgrid<<<(TABN * EKPAD) / 256, 256, 0, stream>>>(rbfg);
    k_embed<<<TN, 256, 0, stream>>>(nodes, embed, x, xb);
    {
        const int total = Ll * 256 * EKPAD + 5 * Ll * 256 * 256 + 256 * 256;
        k_wprep<<<total / 256, 256, 0, stream>>>(me_w1, me_w2, mn_w1, mn_w2, st_w1, st_w2, ro_w1,
                                                 me1T, me2T, mn1T, mn2T, st1T, st2T, ro1T);
    }

    // ---- build all 6 layers' gate tables (z = layer) ----
    const dim3 gT(2, TABN / 128, Ll), gN(2, TN / 64, 1), blk(256);
    gemm_k<1, 0, 128><<<gT, blk, 0, stream>>>(rbfg, me1T, me_b1, ttab, nullptr, nullptr,
                                              TABN, EKPAD,
                                              0, 256 * EKPAD, 256, (long)TABN * 256);
    gemm_k<0, 0, 128><<<gT, blk, 0, stream>>>(ttab, me2T, me_b2, gtab, nullptr, nullptr,
                                              TABN, 256,
                                              (long)TABN * 256, 65536, 256, (long)TABN * 256);

    for (int i = 0; i < Ll; ++i) {
        fused_node16<0, 0><<<TN / 16, 256, 0, stream>>>(
            xb, mn1T + i * 65536, mn_b1 + i * 256,
            mn2T + i * 65536, mn_b2 + i * 256, nmsgb, nullptr, nullptr,
            nullptr, nullptr, nullptr, nullptr, nullptr);
        fused_node16<2, 1><<<TN / 16, 256, 0, stream>>>(
            nullptr, st1T + i * 65536, st_b1 + i * 256,
            st2T + i * 65536, st_b2 + i * 256, nullptr, x, xb,
            dcsr, gtab + (size_t)i * TABN * 256, nmsgb, coff, gsrcs);
    }

    gemm_k<1, 0, 64><<<gN, blk, 0, stream>>>(xb, ro1T, ro_b1, tmpb, nullptr, nullptr,
                                             TN, 256, 0, 0, 0, 0);
    k_readout<<<Bb, 256, 0, stream>>>(tmpb, ro_w2, ro_b2, num_nodes, ev_w, ev_b, out);
}